// Round 13
// baseline (372.973 us; speedup 1.0000x reference)
//
#include <hip/hip_runtime.h>

#define B_ 4
#define C_ 512
#define CI_ 256
#define N_ 4096
#define SCALE_PAM 0.04419417382415922f  // 1/sqrt(512)
#define SCALE_CAM (1.0f/64.0f)          // 1/sqrt(4096)
#define SHIFT_PAM 8.0f

typedef float v4f __attribute__((ext_vector_type(4)));
typedef short v8s __attribute__((ext_vector_type(8)));

__device__ __forceinline__ unsigned short f2bf(float f) {
  unsigned int u = __float_as_uint(f);
  u = (u + 0x7FFFu + ((u >> 16) & 1u)) >> 16;
  return (unsigned short)u;
}
__device__ __forceinline__ float bf2f(unsigned short s) {
  return __uint_as_float(((unsigned int)s) << 16);
}
__device__ __forceinline__ v8s ld8(const unsigned short* p) {
  v8s r; *(int4*)&r = *(const int4*)p; return r;
}
__device__ __forceinline__ v4f mfma16(v8s a, v8s b, v4f c) {
  return __builtin_amdgcn_mfma_f32_16x16x32_bf16(a, b, c, 0, 0, 0);
}
// PK layout: off(r,k) = ((r>>4)*(K>>5) + (k>>5))*512 + (r&15)*32 + (k&31)  [shorts]
// Wave frag load: base + lanelin, lanelin=(lane&15)*32+(lane>>4)*8 -> contiguous 1KB.

// ---------------------------------------------------------------------------
// K_wb: wq/wk/wv fp32 -> w_pk PK(1024,512).  Also zeroes rsum (2048 f32).
// ---------------------------------------------------------------------------
__global__ __launch_bounds__(256) void k_wb(const float* __restrict__ wq,
                                            const float* __restrict__ wk,
                                            const float* __restrict__ wv,
                                            unsigned short* __restrict__ w_pk,
                                            float* __restrict__ rsum) {
  if (blockIdx.x < 8) rsum[blockIdx.x * 256 + threadIdx.x] = 0.f;
  int u = blockIdx.x * 256 + threadIdx.x;
  int blk = u >> 6, wi = (u & 63) * 8;
  int r = (blk >> 4) * 16 + (wi >> 5);
  int k = (blk & 15) * 32 + (wi & 31);
  const float* src = (r < 256) ? &wq[r * 512 + k]
                   : (r < 512) ? &wk[(r - 256) * 512 + k]
                               : &wv[(r - 512) * 512 + k];
  float4 f0 = *(const float4*)src, f1 = *(const float4*)(src + 4);
  ushort4 o0 = { f2bf(f0.x), f2bf(f0.y), f2bf(f0.z), f2bf(f0.w) };
  ushort4 o1 = { f2bf(f1.x), f2bf(f1.y), f2bf(f1.z), f2bf(f1.w) };
  *(ushort4*)&w_pk[u * 8] = o0;
  *(ushort4*)&w_pk[u * 8 + 4] = o1;
}

// ---------------------------------------------------------------------------
// K_xT: x fp32 [b][c][n] -> x_pk PK(4096,512) per batch (rows n, cols c).
// ---------------------------------------------------------------------------
__global__ __launch_bounds__(256) void k_xT(const float* __restrict__ x,
                                            unsigned short* __restrict__ x_pk) {
  const int b = blockIdx.z, c0 = blockIdx.y * 64, n0 = blockIdx.x * 64;
  const int t = threadIdx.x;
  __shared__ unsigned short ts[64 * 72];  // [n][c]
  const int cl = t >> 2, nseg = (t & 3) * 16;
  const float* xr = x + ((size_t)b * C_ + c0 + cl) * N_ + n0 + nseg;
#pragma unroll
  for (int k = 0; k < 4; ++k) {
    float4 f = *(const float4*)(xr + k * 4);
    ts[(nseg + k * 4 + 0) * 72 + cl] = f2bf(f.x);
    ts[(nseg + k * 4 + 1) * 72 + cl] = f2bf(f.y);
    ts[(nseg + k * 4 + 2) * 72 + cl] = f2bf(f.z);
    ts[(nseg + k * 4 + 3) * 72 + cl] = f2bf(f.w);
  }
  __syncthreads();
  unsigned short* dst = x_pk + (size_t)b * N_ * C_;
#pragma unroll
  for (int u = t; u < 512; u += 256) {
    int blk = u >> 6, wi = (u & 63) * 8;
    int rl = (blk >> 1) * 16 + (wi >> 5);
    int kl = (blk & 1) * 32 + (wi & 31);
    int gr = n0 + rl, gk = c0 + kl;
    size_t go = ((size_t)(gr >> 4) * 16 + (gk >> 5)) * 512 + (gr & 15) * 32 + (gk & 31);
    *(int4*)&dst[go] = *(int4*)&ts[rl * 72 + kl];
  }
}

// ---------------------------------------------------------------------------
// K_qkv: y[o][n] = sum_c W[o][c] x[n][c] + b.  128o x 128n tile, 512 thr.
// ---------------------------------------------------------------------------
__global__ __launch_bounds__(512) void k_qkv(
    const unsigned short* __restrict__ w_pk, const unsigned short* __restrict__ x_pk,
    const float* __restrict__ bq, const float* __restrict__ bk, const float* __restrict__ bv,
    unsigned short* __restrict__ q_pk, unsigned short* __restrict__ k_pk,
    unsigned short* __restrict__ v_pk) {
  const int b = blockIdx.z, o0 = blockIdx.y * 128, n0 = blockIdx.x * 128;
  const int t = threadIdx.x, wave = t >> 6, lane = t & 63;
  const int la = lane & 15, quad = lane >> 4;
  const int ow = wave & 1, nw = wave >> 1;
  const int lanelin = la * 32 + quad * 8;
  const unsigned short* xpb = x_pk + (size_t)b * N_ * C_;
  __shared__ unsigned short tp[128 * 136];

  v4f acc[4][2];
#pragma unroll
  for (int i = 0; i < 4; ++i)
#pragma unroll
    for (int j = 0; j < 2; ++j) acc[i][j] = (v4f){0.f, 0.f, 0.f, 0.f};

  const int ar16 = (o0 + ow * 64) >> 4;
  const int br16 = (n0 + nw * 32) >> 4;
#pragma unroll 4
  for (int s = 0; s < 16; ++s) {
    v8s b0 = ld8(&xpb[((size_t)(br16 + 0) * 16 + s) * 512 + lanelin]);
    v8s b1 = ld8(&xpb[((size_t)(br16 + 1) * 16 + s) * 512 + lanelin]);
#pragma unroll
    for (int oi = 0; oi < 4; ++oi) {
      v8s a = ld8(&w_pk[((size_t)(ar16 + oi) * 16 + s) * 512 + lanelin]);
      acc[oi][0] = mfma16(a, b0, acc[oi][0]);
      acc[oi][1] = mfma16(a, b1, acc[oi][1]);
    }
  }

  if (o0 >= 512) {
#pragma unroll
    for (int oi = 0; oi < 4; ++oi)
#pragma unroll
      for (int nj = 0; nj < 2; ++nj)
#pragma unroll
        for (int r = 0; r < 4; ++r) {
          int cl = ow * 64 + oi * 16 + quad * 4 + r;
          int nl = nw * 32 + nj * 16 + la;
          tp[cl * 136 + nl] = f2bf(acc[oi][nj][r] + bv[o0 - 512 + cl]);
        }
    __syncthreads();
    unsigned short* dst = v_pk + (size_t)b * C_ * N_;
#pragma unroll
    for (int u = t; u < 2048; u += 512) {
      int blk = u >> 6, wi = (u & 63) * 8;
      int rl = (blk >> 2) * 16 + (wi >> 5);
      int kl = (blk & 3) * 32 + (wi & 31);
      int gr = (o0 - 512) + rl, gk = n0 + kl;
      size_t go = ((size_t)(gr >> 4) * 128 + (gk >> 5)) * 512 + (gr & 15) * 32 + (gk & 31);
      *(int4*)&dst[go] = *(int4*)&tp[rl * 136 + kl];
    }
  } else {
    const float* bias = (o0 < 256) ? bq : bk;
#pragma unroll
    for (int oi = 0; oi < 4; ++oi)
#pragma unroll
      for (int nj = 0; nj < 2; ++nj)
#pragma unroll
        for (int r = 0; r < 4; ++r) {
          int ol = ow * 64 + oi * 16 + quad * 4 + r;
          int nl = nw * 32 + nj * 16 + la;
          tp[nl * 136 + ol] = f2bf(acc[oi][nj][r] + bias[(o0 & 255) + ol]);
        }
    __syncthreads();
    unsigned short* dst = ((o0 < 256) ? q_pk : k_pk) + (size_t)b * N_ * CI_;
#pragma unroll
    for (int u = t; u < 2048; u += 512) {
      int blk = u >> 6, wi = (u & 63) * 8;
      int rl = (blk >> 2) * 16 + (wi >> 5);
      int kl = (blk & 3) * 32 + (wi & 31);
      int gr = n0 + rl, gk = (o0 & 255) + kl;
      size_t go = ((size_t)(gr >> 4) * 8 + (gk >> 5)) * 512 + (gr & 15) * 32 + (gk & 31);
      *(int4*)&dst[go] = *(int4*)&tp[rl * 136 + kl];
    }
  }
}

// ---------------------------------------------------------------------------
// K_pam v15 (unchanged, verified ~171us): v8 core loop, full j range,
// fused combine epilogue emitting sa_pk + saT_pk.
// ---------------------------------------------------------------------------
__device__ __forceinline__ void kstage(const unsigned short* g, unsigned short* l, int t) {
  __builtin_amdgcn_global_load_lds(
      (const __attribute__((address_space(1))) void*)(g + (size_t)t * 8),
      (__attribute__((address_space(3))) void*)(l + t * 8), 16, 0, 0);
  __builtin_amdgcn_global_load_lds(
      (const __attribute__((address_space(1))) void*)(g + 8192 + (size_t)t * 8),
      (__attribute__((address_space(3))) void*)(l + 8192 + t * 8), 16, 0, 0);
}

__global__ __launch_bounds__(1024) void k_pam(
    const unsigned short* __restrict__ q_pk, const unsigned short* __restrict__ k_pk,
    const unsigned short* __restrict__ v_pk, const float* __restrict__ x,
    const float* __restrict__ gamma_pam,
    unsigned short* __restrict__ sa_pk, unsigned short* __restrict__ saT_pk) {
  const int blk = blockIdx.x;
  const int b = blk & 3, i0 = (blk >> 2) * 64;
  const int t = threadIdx.x, wave = t >> 6, lane = t & 63;
  const int la = lane & 15, quad = lane >> 4;
  const int iw = wave & 3, jw = wave >> 2;
  const int cb = wave * 32;
  const int lanelin = la * 32 + quad * 8;

  __shared__ unsigned short kls[3][16384];  // 3 x 32KB K tiles; reused by epilogue
  __shared__ unsigned short pa[2][4096];    // 64x64 P, XOR-swizzled stride 64
  __shared__ float l_lds[64];
  if (t < 64) l_lds[t] = 0.f;

  const unsigned short* qpk = q_pk + (size_t)b * N_ * CI_;
  const unsigned short* kpk = k_pk + (size_t)b * N_ * CI_;
  const unsigned short* vpk = v_pk + (size_t)b * C_ * N_;

  v8s qf[8];
  {
    const unsigned short* qb = qpk + ((size_t)((i0 >> 4) + iw) * 8) * 512 + lanelin;
#pragma unroll
    for (int s = 0; s < 8; ++s) qf[s] = ld8(qb + s * 512);
  }

  v4f acc[2][4];  // [ct][it]
#pragma unroll
  for (int ct = 0; ct < 2; ++ct)
#pragma unroll
    for (int it = 0; it < 4; ++it) acc[ct][it] = (v4f){0.f, 0.f, 0.f, 0.f};
  float lsum[4] = {0.f, 0.f, 0.f, 0.f};

  // prologue: stage step0 -> kls[0], step1 -> kls[1]; drain step0 only.
  kstage(kpk, kls[0], t);
  kstage(kpk + (size_t)4 * 4096, kls[1], t);
  asm volatile("s_waitcnt vmcnt(2)" ::: "memory");  // DMA_0 done (in-order drain)
  __builtin_amdgcn_s_barrier();
  __builtin_amdgcn_sched_barrier(0);

  int pb = 0;
  for (int step = 0; step < 64; ++step) {
    const int j0 = step * 64;
    // phase 1: V frags (issued FIRST so PV waits vmcnt(2), not 0)
    v8s vf[2][2];
#pragma unroll
    for (int ct = 0; ct < 2; ++ct)
#pragma unroll
      for (int ks = 0; ks < 2; ++ks)
        vf[ct][ks] = ld8(&vpk[((size_t)((cb >> 4) + ct) * 128 + (j0 >> 5) + ks) * 512 + lanelin]);
    __builtin_amdgcn_sched_barrier(0);
    // phase 2: DMA K tile for step+2 into kls[(step+2)%3]
    int jn = j0 + 128; if (jn >= N_) jn = 0;  // tail clamp (data unused)
    kstage(kpk + (size_t)(jn >> 4) * 4096, kls[(step + 2) % 3], t);
    __builtin_amdgcn_sched_barrier(0);
    // phase 3: S = Q K^T from kls[step%3] (staged 2 steps ago; guaranteed by
    // previous step's vmcnt(6)+s_barrier)
    const unsigned short* kb = &kls[step % 3][jw * 4096 + lanelin];
    v4f sA = (v4f){0.f, 0.f, 0.f, 0.f}, sB = sA;
#pragma unroll
    for (int sh = 0; sh < 4; ++sh) {
      sA = mfma16(qf[sh], ld8(kb + sh * 512), sA);
      sB = mfma16(qf[sh + 4], ld8(kb + (sh + 4) * 512), sB);
    }
    // phase 4: P = exp(s*scale - shift), swizzled LDS write
#pragma unroll
    for (int r = 0; r < 4; ++r) {
      float p = __expf((sA[r] + sB[r]) * SCALE_PAM - SHIFT_PAM);
      lsum[r] += p;
      int row = iw * 16 + quad * 4 + r;
      pa[pb][((row << 6) + jw * 16 + la) ^ ((row & 7) << 3)] = f2bf(p);
    }
    // phase 5: fence. lgkmcnt(0): our P writes visible. vmcnt(6): drains the
    // 2 oldest vmem = DMA for step+1 (queue: DMA_{t+1}(2), V_t(4), DMA_{t+2}(2)).
    __builtin_amdgcn_sched_barrier(0);
    asm volatile("s_waitcnt lgkmcnt(0) vmcnt(6)" ::: "memory");
    __builtin_amdgcn_s_barrier();
    __builtin_amdgcn_sched_barrier(0);
    // phase 6: PV: acc[c][i] += V[c][j] * P[i][j]  (compiler waits vmcnt(2) for vf)
    __builtin_amdgcn_s_setprio(1);
#pragma unroll
    for (int it = 0; it < 4; ++it) {
      const int row = it * 16 + la;
      const int sw = (row & 7) << 3;
#pragma unroll
      for (int ks = 0; ks < 2; ++ks) {
        v8s pf; *(int4*)&pf = *(const int4*)&pa[pb][((row << 6) + ks * 32 + quad * 8) ^ sw];
#pragma unroll
        for (int ct = 0; ct < 2; ++ct)
          acc[ct][it] = mfma16(vf[ct][ks], pf, acc[ct][it]);
      }
    }
    __builtin_amdgcn_s_setprio(0);
    pb ^= 1;
  }

  // ---- fused k_combine epilogue ----
#pragma unroll
  for (int r = 0; r < 4; ++r) {
    float v = lsum[r];
    v += __shfl_xor(v, 1); v += __shfl_xor(v, 2);
    v += __shfl_xor(v, 4); v += __shfl_xor(v, 8);
    if (la == 0) atomicAdd(&l_lds[iw * 16 + quad * 4 + r], v);
  }
  __syncthreads();  // l complete; all waves past PV (kls free to reuse)

  const float gpv = gamma_pam[0];
  unsigned short* ts = &kls[0][0];  // stage 1: ts[c][72] (512*72 shorts = 73.7KB)
  unsigned short sv[2][4][4];
#pragma unroll
  for (int ct = 0; ct < 2; ++ct)
#pragma unroll
    for (int it = 0; it < 4; ++it) {
      const int nl = it * 16 + la;
      const float lv = l_lds[nl] * (float)N_;
#pragma unroll
      for (int r = 0; r < 4; ++r) {
        const int c = cb + ct * 16 + quad * 4 + r;
        const float xv = x[((size_t)b * C_ + c) * N_ + i0 + nl];
        const unsigned short h = f2bf(tanhf(fmaf(gpv, acc[ct][it][r] / lv, xv)));
        sv[ct][it][r] = h;
        ts[c * 72 + nl] = h;
      }
    }
  __syncthreads();
  {  // sa_pk: PK(512 c, 4096 n), row-block stride 128
    unsigned short* dst = sa_pk + (size_t)b * C_ * N_;
#pragma unroll
    for (int u = t; u < 4096; u += 1024) {
      int c = u >> 3, n8 = (u & 7) * 8;
      int gn = i0 + n8;
      size_t go = ((size_t)(c >> 4) * 128 + (gn >> 5)) * 512 + (c & 15) * 32 + (gn & 31);
      *(int4*)&dst[go] = *(const int4*)&ts[c * 72 + n8];
    }
  }
  __syncthreads();
  unsigned short* ts2 = &kls[0][0];  // stage 2: ts2[n][520] (64*520 = 66.6KB)
#pragma unroll
  for (int ct = 0; ct < 2; ++ct)
#pragma unroll
    for (int it = 0; it < 4; ++it)
#pragma unroll
      for (int r = 0; r < 4; ++r)
        ts2[(it * 16 + la) * 520 + (cb + ct * 16 + quad * 4 + r)] = sv[ct][it][r];
  __syncthreads();
  {  // saT_pk: PK(4096 n, 512 c), row-block stride 16
    unsigned short* dst = saT_pk + (size_t)b * N_ * C_;
#pragma unroll
    for (int u = t; u < 4096; u += 1024) {
      int nl = u >> 6, c8 = (u & 63) * 8;
      int gn = i0 + nl;
      size_t go = ((size_t)(gn >> 4) * 16 + (c8 >> 5)) * 512 + (gn & 15) * 32 + (c8 & 31);
      *(int4*)&dst[go] = *(const int4*)&ts2[nl * 520 + c8];
    }
  }
}

// ---------------------------------------------------------------------------
// K_cam_e v17: full-K fused softmax numerator (v16 algebra) with restored
// TLP: 512 thr = 8 waves (cw 2 x 32c, dw 4 x 16d) -> 2 waves/SIMD (v16 had
// 1/SIMD, latency-exposed). p = exp(-e) range-safe (|e|<64, tanh bound);
// normalization cancels shift. Writes p bf16 to attn_pk; row sums -> rsum.
// ---------------------------------------------------------------------------
__global__ __launch_bounds__(512) void k_cam_e(const unsigned short* __restrict__ sa_pk,
                                               unsigned short* __restrict__ attn_pk,
                                               float* __restrict__ rsum) {
  const int b = blockIdx.y;
  const int c0 = (blockIdx.x & 7) * 64, d0 = (blockIdx.x >> 3) * 64;
  const int t = threadIdx.x, wave = t >> 6, lane = t & 63;
  const int la = lane & 15, quad = lane >> 4;
  const int cw = wave & 1, dw = wave >> 1;  // cw: 2x32c, dw: 4x16d
  const int lanelin = la * 32 + quad * 8;
  const unsigned short* sb = sa_pk + (size_t)b * C_ * N_;

  v4f acc[2] = {(v4f){0.f, 0.f, 0.f, 0.f}, (v4f){0.f, 0.f, 0.f, 0.f}};
  const int ar16 = (c0 + cw * 32) >> 4;
  const int br16 = (d0 + dw * 16) >> 4;
#pragma unroll 4
  for (int s = 0; s < 128; ++s) {
    v8s a0 = ld8(&sb[((size_t)(ar16 + 0) * 128 + s) * 512 + lanelin]);
    v8s a1 = ld8(&sb[((size_t)(ar16 + 1) * 128 + s) * 512 + lanelin]);
    v8s b0 = ld8(&sb[((size_t)br16 * 128 + s) * 512 + lanelin]);
    acc[0] = mfma16(a0, b0, acc[0]);
    acc[1] = mfma16(a1, b0, acc[1]);
  }
  unsigned short* ab = attn_pk + (size_t)b * C_ * C_;
  float* rs = rsum + b * C_;
  const int d = d0 + dw * 16 + la;
#pragma unroll
  for (int i = 0; i < 2; ++i)
#pragma unroll
    for (int r = 0; r < 4; ++r) {
      const int c = c0 + cw * 32 + i * 16 + quad * 4 + r;
      float p = __expf(-acc[i][r] * SCALE_CAM);
      size_t go = ((size_t)(c >> 4) * 16 + (d >> 5)) * 512 + (c & 15) * 32 + (d & 31);
      ab[go] = f2bf(p);
      float psum = p;
      psum += __shfl_xor(psum, 1); psum += __shfl_xor(psum, 2);
      psum += __shfl_xor(psum, 4); psum += __shfl_xor(psum, 8);
      if (la == 0) atomicAdd(&rs[c], psum);
    }
}

// ---------------------------------------------------------------------------
// K_cam_out v16: out = (gc/(C*rsum[c])) * (p @ sa) + sa.  128c x 128n, 512 thr.
// ---------------------------------------------------------------------------
__global__ __launch_bounds__(512) void k_cam_out(
    const unsigned short* __restrict__ attn_pk, const unsigned short* __restrict__ saT_pk,
    const unsigned short* __restrict__ sa_pk, const float* __restrict__ gamma_cam,
    const float* __restrict__ rsum, float* __restrict__ out) {
  const int b = blockIdx.z, c0 = blockIdx.y * 128, n0 = blockIdx.x * 128;
  const int t = threadIdx.x, wave = t >> 6, lane = t & 63;
  const int la = lane & 15, quad = lane >> 4;
  const int cw = wave & 1, nw = wave >> 1;
  const int lanelin = la * 32 + quad * 8;
  const unsigned short* ab = attn_pk + (size_t)b * C_ * C_;
  const unsigned short* sTb = saT_pk + (size_t)b * N_ * C_;
  const unsigned short* sb = sa_pk + (size_t)b * C_ * N_;

  v4f acc[4][2];
#pragma unroll
  for (int i = 0; i < 4; ++i)
#pragma unroll
    for (int j = 0; j < 2; ++j) acc[i][j] = (v4f){0.f, 0.f, 0.f, 0.f};

  const int ar16 = (c0 + cw * 64) >> 4;
  const int br16 = (n0 + nw * 32) >> 4;
#pragma unroll 4
  for (int s = 0; s < 16; ++s) {
    v8s b0 = ld8(&sTb[((size_t)(br16 + 0) * 16 + s) * 512 + lanelin]);
    v8s b1 = ld8(&sTb[((size_t)(br16 + 1) * 16 + s) * 512 + lanelin]);
#pragma unroll
    for (int ci = 0; ci < 4; ++ci) {
      v8s a = ld8(&ab[((size_t)(ar16 + ci) * 16 + s) * 512 + lanelin]);
      acc[ci][0] = mfma16(a, b0, acc[ci][0]);
      acc[ci][1] = mfma16(a, b1, acc[ci][1]);
    }
  }
  const float gcs = gamma_cam[0] * (1.0f / (float)C_);
  const float* rs = rsum + b * C_;
#pragma unroll
  for (int ci = 0; ci < 4; ++ci)
#pragma unroll
    for (int nj = 0; nj < 2; ++nj)
#pragma unroll
      for (int r = 0; r < 4; ++r) {
        int c = c0 + cw * 64 + ci * 16 + quad * 4 + r;
        int n = n0 + nw * 32 + nj * 16 + la;
        float sc = gcs / rs[c];
        size_t pko = ((size_t)(c >> 4) * 128 + (n >> 5)) * 512 + (c & 15) * 32 + (n & 31);
        out[((size_t)b * C_ + c) * N_ + n] = fmaf(sc, acc[ci][nj][r], bf2f(sb[pko]));
      }
}

// ---------------------------------------------------------------------------
extern "C" void kernel_launch(void* const* d_in, const int* in_sizes, int n_in,
                              void* d_out, int out_size, void* d_ws, size_t ws_size,
                              hipStream_t stream) {
  const float* x  = (const float*)d_in[0];
  const float* wq = (const float*)d_in[1];
  const float* bq = (const float*)d_in[2];
  const float* wk = (const float*)d_in[3];
  const float* bk = (const float*)d_in[4];
  const float* wv = (const float*)d_in[5];
  const float* bv = (const float*)d_in[6];
  const float* gp = (const float*)d_in[7];
  const float* gc = (const float*)d_in[8];
  float* out = (float*)d_out;

  char* ws = (char*)d_ws;
  // Region map (max used = 84.95 MB):
  //  A 0        : x_pk (16.78M)   -> later at_pk (2.1M)
  //  B 16.78M   : w_pk (1.05M)
  //  C 17.83M   : q_pk (8.39M)    (live through k_pam)
  //  D 26.21M   : k_pk (8.39M)    (live through k_pam)
  //  E 34.60M   : v_pk (16.78M)   (live through k_pam)
  //  F 51.38M   : sa_pk (16.78M)
  //  G 68.16M   : saT_pk (16.78M)
  //  H 84.93M   : rsum (8KB)
  unsigned short* x_pk   = (unsigned short*)(ws);
  unsigned short* w_pk   = (unsigned short*)(ws + 16777216);
  unsigned short* q_pk   = (unsigned short*)(ws + 17825792);
  unsigned short* k_pk   = (unsigned short*)(ws + 26214400);
  unsigned short* v_pk   = (unsigned short*)(ws + 34603008);
  unsigned short* sa_pk  = (unsigned short*)(ws + 51380224);
  unsigned short* saT_pk = (unsigned short*)(ws + 68157440);
  float*          rsum   = (float*)(ws + 84934656);
  unsigned short* at_pk  = (unsigned short*)(ws);              // reuse A

  k_xT<<<dim3(64, 8, B_), 256, 0, stream>>>(x, x_pk);
  k_wb<<<256, 256, 0, stream>>>(wq, wk, wv, w_pk, rsum);
  k_qkv<<<dim3(32, 8, B_), 512, 0, stream>>>(w_pk, x_pk, bq, bk, bv, q_pk, k_pk, v_pk);
  k_pam<<<256, 1024, 0, stream>>>(q_pk, k_pk, v_pk, x, gp, sa_pk, saT_pk);
  k_cam_e<<<dim3(64, B_), 512, 0, stream>>>(sa_pk, at_pk, rsum);
  k_cam_out<<<dim3(32, 4, B_), 512, 0, stream>>>(at_pk, saT_pk, sa_pk, gc, rsum, out);
}

// Round 14
// 361.022 us; speedup vs baseline: 1.0331x; 1.0331x over previous
//
#include <hip/hip_runtime.h>

#define B_ 4
#define C_ 512
#define CI_ 256
#define N_ 4096
#define SCALE_PAM 0.04419417382415922f  // 1/sqrt(512)
#define SCALE_CAM (1.0f/64.0f)          // 1/sqrt(4096)
#define SHIFT_PAM 8.0f

typedef float v4f __attribute__((ext_vector_type(4)));
typedef short v8s __attribute__((ext_vector_type(8)));

__device__ __forceinline__ unsigned short f2bf(float f) {
  unsigned int u = __float_as_uint(f);
  u = (u + 0x7FFFu + ((u >> 16) & 1u)) >> 16;
  return (unsigned short)u;
}
__device__ __forceinline__ float bf2f(unsigned short s) {
  return __uint_as_float(((unsigned int)s) << 16);
}
__device__ __forceinline__ v8s ld8(const unsigned short* p) {
  v8s r; *(int4*)&r = *(const int4*)p; return r;
}
__device__ __forceinline__ v4f mfma16(v8s a, v8s b, v4f c) {
  return __builtin_amdgcn_mfma_f32_16x16x32_bf16(a, b, c, 0, 0, 0);
}
// PK layout: off(r,k) = ((r>>4)*(K>>5) + (k>>5))*512 + (r&15)*32 + (k&31)  [shorts]
// Wave frag load: base + lanelin, lanelin=(lane&15)*32+(lane>>4)*8 -> contiguous 1KB.

// ---------------------------------------------------------------------------
// K_wb: wq/wk/wv fp32 -> w_pk PK(1024,512).
// ---------------------------------------------------------------------------
__global__ __launch_bounds__(256) void k_wb(const float* __restrict__ wq,
                                            const float* __restrict__ wk,
                                            const float* __restrict__ wv,
                                            unsigned short* __restrict__ w_pk) {
  int u = blockIdx.x * 256 + threadIdx.x;
  int blk = u >> 6, wi = (u & 63) * 8;
  int r = (blk >> 4) * 16 + (wi >> 5);
  int k = (blk & 15) * 32 + (wi & 31);
  const float* src = (r < 256) ? &wq[r * 512 + k]
                   : (r < 512) ? &wk[(r - 256) * 512 + k]
                               : &wv[(r - 512) * 512 + k];
  float4 f0 = *(const float4*)src, f1 = *(const float4*)(src + 4);
  ushort4 o0 = { f2bf(f0.x), f2bf(f0.y), f2bf(f0.z), f2bf(f0.w) };
  ushort4 o1 = { f2bf(f1.x), f2bf(f1.y), f2bf(f1.z), f2bf(f1.w) };
  *(ushort4*)&w_pk[u * 8] = o0;
  *(ushort4*)&w_pk[u * 8 + 4] = o1;
}

// ---------------------------------------------------------------------------
// K_xT: x fp32 [b][c][n] -> x_pk PK(4096,512) per batch (rows n, cols c).
// ---------------------------------------------------------------------------
__global__ __launch_bounds__(256) void k_xT(const float* __restrict__ x,
                                            unsigned short* __restrict__ x_pk) {
  const int b = blockIdx.z, c0 = blockIdx.y * 64, n0 = blockIdx.x * 64;
  const int t = threadIdx.x;
  __shared__ unsigned short ts[64 * 72];  // [n][c]
  const int cl = t >> 2, nseg = (t & 3) * 16;
  const float* xr = x + ((size_t)b * C_ + c0 + cl) * N_ + n0 + nseg;
#pragma unroll
  for (int k = 0; k < 4; ++k) {
    float4 f = *(const float4*)(xr + k * 4);
    ts[(nseg + k * 4 + 0) * 72 + cl] = f2bf(f.x);
    ts[(nseg + k * 4 + 1) * 72 + cl] = f2bf(f.y);
    ts[(nseg + k * 4 + 2) * 72 + cl] = f2bf(f.z);
    ts[(nseg + k * 4 + 3) * 72 + cl] = f2bf(f.w);
  }
  __syncthreads();
  unsigned short* dst = x_pk + (size_t)b * N_ * C_;
#pragma unroll
  for (int u = t; u < 512; u += 256) {
    int blk = u >> 6, wi = (u & 63) * 8;
    int rl = (blk >> 1) * 16 + (wi >> 5);
    int kl = (blk & 1) * 32 + (wi & 31);
    int gr = n0 + rl, gk = c0 + kl;
    size_t go = ((size_t)(gr >> 4) * 16 + (gk >> 5)) * 512 + (gr & 15) * 32 + (gk & 31);
    *(int4*)&dst[go] = *(int4*)&ts[rl * 72 + kl];
  }
}

// ---------------------------------------------------------------------------
// K_qkv: y[o][n] = sum_c W[o][c] x[n][c] + b.  128o x 128n tile, 512 thr.
// ---------------------------------------------------------------------------
__global__ __launch_bounds__(512) void k_qkv(
    const unsigned short* __restrict__ w_pk, const unsigned short* __restrict__ x_pk,
    const float* __restrict__ bq, const float* __restrict__ bk, const float* __restrict__ bv,
    unsigned short* __restrict__ q_pk, unsigned short* __restrict__ k_pk,
    unsigned short* __restrict__ v_pk) {
  const int b = blockIdx.z, o0 = blockIdx.y * 128, n0 = blockIdx.x * 128;
  const int t = threadIdx.x, wave = t >> 6, lane = t & 63;
  const int la = lane & 15, quad = lane >> 4;
  const int ow = wave & 1, nw = wave >> 1;
  const int lanelin = la * 32 + quad * 8;
  const unsigned short* xpb = x_pk + (size_t)b * N_ * C_;
  __shared__ unsigned short tp[128 * 136];

  v4f acc[4][2];
#pragma unroll
  for (int i = 0; i < 4; ++i)
#pragma unroll
    for (int j = 0; j < 2; ++j) acc[i][j] = (v4f){0.f, 0.f, 0.f, 0.f};

  const int ar16 = (o0 + ow * 64) >> 4;
  const int br16 = (n0 + nw * 32) >> 4;
#pragma unroll 4
  for (int s = 0; s < 16; ++s) {
    v8s b0 = ld8(&xpb[((size_t)(br16 + 0) * 16 + s) * 512 + lanelin]);
    v8s b1 = ld8(&xpb[((size_t)(br16 + 1) * 16 + s) * 512 + lanelin]);
#pragma unroll
    for (int oi = 0; oi < 4; ++oi) {
      v8s a = ld8(&w_pk[((size_t)(ar16 + oi) * 16 + s) * 512 + lanelin]);
      acc[oi][0] = mfma16(a, b0, acc[oi][0]);
      acc[oi][1] = mfma16(a, b1, acc[oi][1]);
    }
  }

  if (o0 >= 512) {
#pragma unroll
    for (int oi = 0; oi < 4; ++oi)
#pragma unroll
      for (int nj = 0; nj < 2; ++nj)
#pragma unroll
        for (int r = 0; r < 4; ++r) {
          int cl = ow * 64 + oi * 16 + quad * 4 + r;
          int nl = nw * 32 + nj * 16 + la;
          tp[cl * 136 + nl] = f2bf(acc[oi][nj][r] + bv[o0 - 512 + cl]);
        }
    __syncthreads();
    unsigned short* dst = v_pk + (size_t)b * C_ * N_;
#pragma unroll
    for (int u = t; u < 2048; u += 512) {
      int blk = u >> 6, wi = (u & 63) * 8;
      int rl = (blk >> 2) * 16 + (wi >> 5);
      int kl = (blk & 3) * 32 + (wi & 31);
      int gr = (o0 - 512) + rl, gk = n0 + kl;
      size_t go = ((size_t)(gr >> 4) * 128 + (gk >> 5)) * 512 + (gr & 15) * 32 + (gk & 31);
      *(int4*)&dst[go] = *(int4*)&tp[rl * 136 + kl];
    }
  } else {
    const float* bias = (o0 < 256) ? bq : bk;
#pragma unroll
    for (int oi = 0; oi < 4; ++oi)
#pragma unroll
      for (int nj = 0; nj < 2; ++nj)
#pragma unroll
        for (int r = 0; r < 4; ++r) {
          int ol = ow * 64 + oi * 16 + quad * 4 + r;
          int nl = nw * 32 + nj * 16 + la;
          tp[nl * 136 + ol] = f2bf(acc[oi][nj][r] + bias[(o0 & 255) + ol]);
        }
    __syncthreads();
    unsigned short* dst = ((o0 < 256) ? q_pk : k_pk) + (size_t)b * N_ * CI_;
#pragma unroll
    for (int u = t; u < 2048; u += 512) {
      int blk = u >> 6, wi = (u & 63) * 8;
      int rl = (blk >> 2) * 16 + (wi >> 5);
      int kl = (blk & 3) * 32 + (wi & 31);
      int gr = n0 + rl, gk = (o0 & 255) + kl;
      size_t go = ((size_t)(gr >> 4) * 8 + (gk >> 5)) * 512 + (gr & 15) * 32 + (gk & 31);
      *(int4*)&dst[go] = *(int4*)&tp[rl * 136 + kl];
    }
  }
}

// ---------------------------------------------------------------------------
// K_pam v15 (verified best, 360.7us total): v8 core loop, full j range,
// fused combine epilogue emitting sa_pk + saT_pk.
// ---------------------------------------------------------------------------
__device__ __forceinline__ void kstage(const unsigned short* g, unsigned short* l, int t) {
  __builtin_amdgcn_global_load_lds(
      (const __attribute__((address_space(1))) void*)(g + (size_t)t * 8),
      (__attribute__((address_space(3))) void*)(l + t * 8), 16, 0, 0);
  __builtin_amdgcn_global_load_lds(
      (const __attribute__((address_space(1))) void*)(g + 8192 + (size_t)t * 8),
      (__attribute__((address_space(3))) void*)(l + 8192 + t * 8), 16, 0, 0);
}

__global__ __launch_bounds__(1024) void k_pam(
    const unsigned short* __restrict__ q_pk, const unsigned short* __restrict__ k_pk,
    const unsigned short* __restrict__ v_pk, const float* __restrict__ x,
    const float* __restrict__ gamma_pam,
    unsigned short* __restrict__ sa_pk, unsigned short* __restrict__ saT_pk) {
  const int blk = blockIdx.x;
  const int b = blk & 3, i0 = (blk >> 2) * 64;
  const int t = threadIdx.x, wave = t >> 6, lane = t & 63;
  const int la = lane & 15, quad = lane >> 4;
  const int iw = wave & 3, jw = wave >> 2;
  const int cb = wave * 32;
  const int lanelin = la * 32 + quad * 8;

  __shared__ unsigned short kls[3][16384];  // 3 x 32KB K tiles; reused by epilogue
  __shared__ unsigned short pa[2][4096];    // 64x64 P, XOR-swizzled stride 64
  __shared__ float l_lds[64];
  if (t < 64) l_lds[t] = 0.f;

  const unsigned short* qpk = q_pk + (size_t)b * N_ * CI_;
  const unsigned short* kpk = k_pk + (size_t)b * N_ * CI_;
  const unsigned short* vpk = v_pk + (size_t)b * C_ * N_;

  v8s qf[8];
  {
    const unsigned short* qb = qpk + ((size_t)((i0 >> 4) + iw) * 8) * 512 + lanelin;
#pragma unroll
    for (int s = 0; s < 8; ++s) qf[s] = ld8(qb + s * 512);
  }

  v4f acc[2][4];  // [ct][it]
#pragma unroll
  for (int ct = 0; ct < 2; ++ct)
#pragma unroll
    for (int it = 0; it < 4; ++it) acc[ct][it] = (v4f){0.f, 0.f, 0.f, 0.f};
  float lsum[4] = {0.f, 0.f, 0.f, 0.f};

  // prologue: stage step0 -> kls[0], step1 -> kls[1]; drain step0 only.
  kstage(kpk, kls[0], t);
  kstage(kpk + (size_t)4 * 4096, kls[1], t);
  asm volatile("s_waitcnt vmcnt(2)" ::: "memory");  // DMA_0 done (in-order drain)
  __builtin_amdgcn_s_barrier();
  __builtin_amdgcn_sched_barrier(0);

  int pb = 0;
  for (int step = 0; step < 64; ++step) {
    const int j0 = step * 64;
    // phase 1: V frags (issued FIRST so PV waits vmcnt(2), not 0)
    v8s vf[2][2];
#pragma unroll
    for (int ct = 0; ct < 2; ++ct)
#pragma unroll
      for (int ks = 0; ks < 2; ++ks)
        vf[ct][ks] = ld8(&vpk[((size_t)((cb >> 4) + ct) * 128 + (j0 >> 5) + ks) * 512 + lanelin]);
    __builtin_amdgcn_sched_barrier(0);
    // phase 2: DMA K tile for step+2 into kls[(step+2)%3]
    int jn = j0 + 128; if (jn >= N_) jn = 0;  // tail clamp (data unused)
    kstage(kpk + (size_t)(jn >> 4) * 4096, kls[(step + 2) % 3], t);
    __builtin_amdgcn_sched_barrier(0);
    // phase 3: S = Q K^T from kls[step%3] (staged 2 steps ago; guaranteed by
    // previous step's vmcnt(6)+s_barrier)
    const unsigned short* kb = &kls[step % 3][jw * 4096 + lanelin];
    v4f sA = (v4f){0.f, 0.f, 0.f, 0.f}, sB = sA;
#pragma unroll
    for (int sh = 0; sh < 4; ++sh) {
      sA = mfma16(qf[sh], ld8(kb + sh * 512), sA);
      sB = mfma16(qf[sh + 4], ld8(kb + (sh + 4) * 512), sB);
    }
    // phase 4: P = exp(s*scale - shift), swizzled LDS write
#pragma unroll
    for (int r = 0; r < 4; ++r) {
      float p = __expf((sA[r] + sB[r]) * SCALE_PAM - SHIFT_PAM);
      lsum[r] += p;
      int row = iw * 16 + quad * 4 + r;
      pa[pb][((row << 6) + jw * 16 + la) ^ ((row & 7) << 3)] = f2bf(p);
    }
    // phase 5: fence. lgkmcnt(0): our P writes visible. vmcnt(6): drains the
    // 2 oldest vmem = DMA for step+1 (queue: DMA_{t+1}(2), V_t(4), DMA_{t+2}(2)).
    __builtin_amdgcn_sched_barrier(0);
    asm volatile("s_waitcnt lgkmcnt(0) vmcnt(6)" ::: "memory");
    __builtin_amdgcn_s_barrier();
    __builtin_amdgcn_sched_barrier(0);
    // phase 6: PV: acc[c][i] += V[c][j] * P[i][j]  (compiler waits vmcnt(2) for vf)
    __builtin_amdgcn_s_setprio(1);
#pragma unroll
    for (int it = 0; it < 4; ++it) {
      const int row = it * 16 + la;
      const int sw = (row & 7) << 3;
#pragma unroll
      for (int ks = 0; ks < 2; ++ks) {
        v8s pf; *(int4*)&pf = *(const int4*)&pa[pb][((row << 6) + ks * 32 + quad * 8) ^ sw];
#pragma unroll
        for (int ct = 0; ct < 2; ++ct)
          acc[ct][it] = mfma16(vf[ct][ks], pf, acc[ct][it]);
      }
    }
    __builtin_amdgcn_s_setprio(0);
    pb ^= 1;
  }

  // ---- fused k_combine epilogue ----
#pragma unroll
  for (int r = 0; r < 4; ++r) {
    float v = lsum[r];
    v += __shfl_xor(v, 1); v += __shfl_xor(v, 2);
    v += __shfl_xor(v, 4); v += __shfl_xor(v, 8);
    if (la == 0) atomicAdd(&l_lds[iw * 16 + quad * 4 + r], v);
  }
  __syncthreads();  // l complete; all waves past PV (kls free to reuse)

  const float gpv = gamma_pam[0];
  unsigned short* ts = &kls[0][0];  // stage 1: ts[c][72] (512*72 shorts = 73.7KB)
  unsigned short sv[2][4][4];
#pragma unroll
  for (int ct = 0; ct < 2; ++ct)
#pragma unroll
    for (int it = 0; it < 4; ++it) {
      const int nl = it * 16 + la;
      const float lv = l_lds[nl] * (float)N_;
#pragma unroll
      for (int r = 0; r < 4; ++r) {
        const int c = cb + ct * 16 + quad * 4 + r;
        const float xv = x[((size_t)b * C_ + c) * N_ + i0 + nl];
        const unsigned short h = f2bf(tanhf(fmaf(gpv, acc[ct][it][r] / lv, xv)));
        sv[ct][it][r] = h;
        ts[c * 72 + nl] = h;
      }
    }
  __syncthreads();
  {  // sa_pk: PK(512 c, 4096 n), row-block stride 128
    unsigned short* dst = sa_pk + (size_t)b * C_ * N_;
#pragma unroll
    for (int u = t; u < 4096; u += 1024) {
      int c = u >> 3, n8 = (u & 7) * 8;
      int gn = i0 + n8;
      size_t go = ((size_t)(c >> 4) * 128 + (gn >> 5)) * 512 + (c & 15) * 32 + (gn & 31);
      *(int4*)&dst[go] = *(const int4*)&ts[c * 72 + n8];
    }
  }
  __syncthreads();
  unsigned short* ts2 = &kls[0][0];  // stage 2: ts2[n][520] (64*520 = 66.6KB)
#pragma unroll
  for (int ct = 0; ct < 2; ++ct)
#pragma unroll
    for (int it = 0; it < 4; ++it)
#pragma unroll
      for (int r = 0; r < 4; ++r)
        ts2[(it * 16 + la) * 520 + (cb + ct * 16 + quad * 4 + r)] = sv[ct][it][r];
  __syncthreads();
  {  // saT_pk: PK(4096 n, 512 c), row-block stride 16
    unsigned short* dst = saT_pk + (size_t)b * N_ * C_;
#pragma unroll
    for (int u = t; u < 4096; u += 1024) {
      int nl = u >> 6, c8 = (u & 63) * 8;
      int gn = i0 + nl;
      size_t go = ((size_t)(gn >> 4) * 16 + (c8 >> 5)) * 512 + (gn & 15) * 32 + (c8 & 31);
      *(int4*)&dst[go] = *(const int4*)&ts2[nl * 520 + c8];
    }
  }
}

// ---------------------------------------------------------------------------
// K_cam_e: e_part[ks][b][c][d] = scale * sum_n sa_c sa_d.  64x64 tile, ks4.
// ---------------------------------------------------------------------------
__global__ __launch_bounds__(256) void k_cam_e(const unsigned short* __restrict__ sa_pk,
                                               float* __restrict__ e_part) {
  const int b = blockIdx.z, ks = blockIdx.y;
  const int c0 = (blockIdx.x & 7) * 64, d0 = (blockIdx.x >> 3) * 64;
  const int t = threadIdx.x, wave = t >> 6, lane = t & 63;
  const int la = lane & 15, quad = lane >> 4;
  const int cw = wave & 1, dw = wave >> 1;
  const int lanelin = la * 32 + quad * 8;
  const unsigned short* sb = sa_pk + (size_t)b * C_ * N_;

  v4f acc[2][2];
#pragma unroll
  for (int i = 0; i < 2; ++i)
#pragma unroll
    for (int j = 0; j < 2; ++j) acc[i][j] = (v4f){0.f, 0.f, 0.f, 0.f};

  const int ar16 = (c0 + cw * 32) >> 4;
  const int br16 = (d0 + dw * 32) >> 4;
#pragma unroll 4
  for (int s = 0; s < 32; ++s) {
    const int k32 = ks * 32 + s;
    v8s a0 = ld8(&sb[((size_t)(ar16 + 0) * 128 + k32) * 512 + lanelin]);
    v8s a1 = ld8(&sb[((size_t)(ar16 + 1) * 128 + k32) * 512 + lanelin]);
    v8s b0 = ld8(&sb[((size_t)(br16 + 0) * 128 + k32) * 512 + lanelin]);
    v8s b1 = ld8(&sb[((size_t)(br16 + 1) * 128 + k32) * 512 + lanelin]);
    acc[0][0] = mfma16(a0, b0, acc[0][0]);
    acc[0][1] = mfma16(a0, b1, acc[0][1]);
    acc[1][0] = mfma16(a1, b0, acc[1][0]);
    acc[1][1] = mfma16(a1, b1, acc[1][1]);
  }
  float* ep = e_part + ((size_t)(ks * B_ + b)) * C_ * C_;
#pragma unroll
  for (int i = 0; i < 2; ++i)
#pragma unroll
    for (int j = 0; j < 2; ++j)
#pragma unroll
      for (int r = 0; r < 4; ++r) {
        int c = c0 + cw * 32 + i * 16 + quad * 4 + r;
        int d = d0 + dw * 32 + j * 16 + la;
        ep[(size_t)c * C_ + d] = acc[i][j][r] * SCALE_CAM;
      }
}

// ---------------------------------------------------------------------------
// K_cam_softmax: min-trick softmax over 4 parts -> attn_pk PK(512,512).
// ---------------------------------------------------------------------------
__global__ __launch_bounds__(64) void k_cam_softmax(const float* __restrict__ e_part,
                                                    unsigned short* __restrict__ attn_pk) {
  const int c = blockIdx.x, b = blockIdx.y, lane = threadIdx.x;
  size_t roff = ((size_t)b * C_ + c) * C_;
  float vals[8];
#pragma unroll
  for (int r = 0; r < 8; ++r) {
    int d = lane + r * 64;
    float s = 0.f;
#pragma unroll
    for (int p = 0; p < 4; ++p) s += e_part[(size_t)(p * B_) * C_ * C_ + roff + d];
    vals[r] = s;
  }
  float mn = vals[0];
#pragma unroll
  for (int r = 1; r < 8; ++r) mn = fminf(mn, vals[r]);
#pragma unroll
  for (int m = 32; m >= 1; m >>= 1) mn = fminf(mn, __shfl_xor(mn, m));
  float sum = 0.f;
#pragma unroll
  for (int r = 0; r < 8; ++r) { vals[r] = __expf(mn - vals[r]); sum += vals[r]; }
#pragma unroll
  for (int m = 32; m >= 1; m >>= 1) sum += __shfl_xor(sum, m);
  float sc = (1.0f / (float)C_) / sum;
  unsigned short* ab = attn_pk + (size_t)b * C_ * C_;
#pragma unroll
  for (int r = 0; r < 8; ++r) {
    int d = lane + r * 64;
    size_t go = ((size_t)(c >> 4) * 16 + (d >> 5)) * 512 + (c & 15) * 32 + (d & 31);
    ab[go] = f2bf(vals[r] * sc);
  }
}

// ---------------------------------------------------------------------------
// K_cam_out: out = gc * (attn @ sa) + sa.  128c x 128n tile, 512 thr.
// ---------------------------------------------------------------------------
__global__ __launch_bounds__(512) void k_cam_out(
    const unsigned short* __restrict__ attn_pk, const unsigned short* __restrict__ saT_pk,
    const unsigned short* __restrict__ sa_pk, const float* __restrict__ gamma_cam,
    float* __restrict__ out) {
  const int b = blockIdx.z, c0 = blockIdx.y * 128, n0 = blockIdx.x * 128;
  const int t = threadIdx.x, wave = t >> 6, lane = t & 63;
  const int la = lane & 15, quad = lane >> 4;
  const int cw = wave & 1, nw = wave >> 1;
  const int lanelin = la * 32 + quad * 8;
  const unsigned short* ab = attn_pk + (size_t)b * C_ * C_;
  const unsigned short* sTb = saT_pk + (size_t)b * N_ * C_;
  const unsigned short* sb = sa_pk + (size_t)b * C_ * N_;

  v4f acc[4][2];
#pragma unroll
  for (int i = 0; i < 4; ++i)
#pragma unroll
    for (int j = 0; j < 2; ++j) acc[i][j] = (v4f){0.f, 0.f, 0.f, 0.f};

  const int ar16 = (c0 + cw * 64) >> 4;
  const int br16 = (n0 + nw * 32) >> 4;
#pragma unroll 4
  for (int s = 0; s < 16; ++s) {
    v8s b0 = ld8(&sTb[((size_t)(br16 + 0) * 16 + s) * 512 + lanelin]);
    v8s b1 = ld8(&sTb[((size_t)(br16 + 1) * 16 + s) * 512 + lanelin]);
#pragma unroll
    for (int ci = 0; ci < 4; ++ci) {
      v8s a = ld8(&ab[((size_t)(ar16 + ci) * 16 + s) * 512 + lanelin]);
      acc[ci][0] = mfma16(a, b0, acc[ci][0]);
      acc[ci][1] = mfma16(a, b1, acc[ci][1]);
    }
  }
  const float gc = gamma_cam[0];
#pragma unroll
  for (int ci = 0; ci < 4; ++ci)
#pragma unroll
    for (int nj = 0; nj < 2; ++nj)
#pragma unroll
      for (int r = 0; r < 4; ++r) {
        int c = c0 + cw * 64 + ci * 16 + quad * 4 + r;
        int n = n0 + nw * 32 + nj * 16 + la;
        size_t pko = ((size_t)(c >> 4) * 128 + (n >> 5)) * 512 + (c & 15) * 32 + (n & 31);
        out[((size_t)b * C_ + c) * N_ + n] = fmaf(gc, acc[ci][nj][r], bf2f(sb[pko]));
      }
}

// ---------------------------------------------------------------------------
extern "C" void kernel_launch(void* const* d_in, const int* in_sizes, int n_in,
                              void* d_out, int out_size, void* d_ws, size_t ws_size,
                              hipStream_t stream) {
  const float* x  = (const float*)d_in[0];
  const float* wq = (const float*)d_in[1];
  const float* bq = (const float*)d_in[2];
  const float* wk = (const float*)d_in[3];
  const float* bk = (const float*)d_in[4];
  const float* wv = (const float*)d_in[5];
  const float* bv = (const float*)d_in[6];
  const float* gp = (const float*)d_in[7];
  const float* gc = (const float*)d_in[8];
  float* out = (float*)d_out;

  char* ws = (char*)d_ws;
  // Region map (k_combine fused into k_pam; max used = 84.9 MB):
  //  A 0        : x_pk (16.78M)   -> later at_pk (2.1M)
  //  B 16.78M   : w_pk (1.05M)
  //  C 17.83M   : q_pk (8.39M)    (live through k_pam)
  //  D 26.21M   : k_pk (8.39M)    (live through k_pam)
  //  E 34.60M   : v_pk (16.78M)   -> later ep (16.78M)
  //  F 51.38M   : sa_pk (16.78M)
  //  G 68.16M   : saT_pk (16.78M)
  unsigned short* x_pk   = (unsigned short*)(ws);
  unsigned short* w_pk   = (unsigned short*)(ws + 16777216);
  unsigned short* q_pk   = (unsigned short*)(ws + 17825792);
  unsigned short* k_pk   = (unsigned short*)(ws + 26214400);
  unsigned short* v_pk   = (unsigned short*)(ws + 34603008);
  unsigned short* sa_pk  = (unsigned short*)(ws + 51380224);
  unsigned short* saT_pk = (unsigned short*)(ws + 68157440);
  float*          ep     = (float*)(ws + 34603008);            // reuse E
  unsigned short* at_pk  = (unsigned short*)(ws);              // reuse A

  k_xT<<<dim3(64, 8, B_), 256, 0, stream>>>(x, x_pk);
  k_wb<<<256, 256, 0, stream>>>(wq, wk, wv, w_pk);
  k_qkv<<<dim3(32, 8, B_), 512, 0, stream>>>(w_pk, x_pk, bq, bk, bv, q_pk, k_pk, v_pk);
  k_pam<<<256, 1024, 0, stream>>>(q_pk, k_pk, v_pk, x, gp, sa_pk, saT_pk);
  k_cam_e<<<dim3(64, 4, B_), 256, 0, stream>>>(sa_pk, ep);
  k_cam_softmax<<<dim3(C_, B_), 64, 0, stream>>>(ep, at_pk);
  k_cam_out<<<dim3(32, 4, B_), 512, 0, stream>>>(at_pk, saT_pk, sa_pk, gc, out);
}

// Round 15
// 358.207 us; speedup vs baseline: 1.0412x; 1.0079x over previous
//
#include <hip/hip_runtime.h>

#define B_ 4
#define C_ 512
#define CI_ 256
#define N_ 4096
#define SCALE_PAM 0.04419417382415922f  // 1/sqrt(512)
#define SCALE_CAM (1.0f/64.0f)          // 1/sqrt(4096)
#define SHIFT_PAM 8.0f

typedef float v4f __attribute__((ext_vector_type(4)));
typedef short v8s __attribute__((ext_vector_type(8)));

__device__ __forceinline__ unsigned short f2bf(float f) {
  unsigned int u = __float_as_uint(f);
  u = (u + 0x7FFFu + ((u >> 16) & 1u)) >> 16;
  return (unsigned short)u;
}
__device__ __forceinline__ float bf2f(unsigned short s) {
  return __uint_as_float(((unsigned int)s) << 16);
}
__device__ __forceinline__ v8s ld8(const unsigned short* p) {
  v8s r; *(int4*)&r = *(const int4*)p; return r;
}
__device__ __forceinline__ v4f mfma16(v8s a, v8s b, v4f c) {
  return __builtin_amdgcn_mfma_f32_16x16x32_bf16(a, b, c, 0, 0, 0);
}
// PK layout: off(r,k) = ((r>>4)*(K>>5) + (k>>5))*512 + (r&15)*32 + (k&31)  [shorts]
// Wave frag load: base + lanelin, lanelin=(lane&15)*32+(lane>>4)*8 -> contiguous 1KB.

// ---------------------------------------------------------------------------
// K_wb: wq/wk/wv fp32 -> w_pk PK(1024,512).
// ---------------------------------------------------------------------------
__global__ __launch_bounds__(256) void k_wb(const float* __restrict__ wq,
                                            const float* __restrict__ wk,
                                            const float* __restrict__ wv,
                                            unsigned short* __restrict__ w_pk) {
  int u = blockIdx.x * 256 + threadIdx.x;
  int blk = u >> 6, wi = (u & 63) * 8;
  int r = (blk >> 4) * 16 + (wi >> 5);
  int k = (blk & 15) * 32 + (wi & 31);
  const float* src = (r < 256) ? &wq[r * 512 + k]
                   : (r < 512) ? &wk[(r - 256) * 512 + k]
                               : &wv[(r - 512) * 512 + k];
  float4 f0 = *(const float4*)src, f1 = *(const float4*)(src + 4);
  ushort4 o0 = { f2bf(f0.x), f2bf(f0.y), f2bf(f0.z), f2bf(f0.w) };
  ushort4 o1 = { f2bf(f1.x), f2bf(f1.y), f2bf(f1.z), f2bf(f1.w) };
  *(ushort4*)&w_pk[u * 8] = o0;
  *(ushort4*)&w_pk[u * 8 + 4] = o1;
}

// ---------------------------------------------------------------------------
// K_xT: x fp32 [b][c][n] -> x_pk PK(4096,512) per batch (rows n, cols c).
// ---------------------------------------------------------------------------
__global__ __launch_bounds__(256) void k_xT(const float* __restrict__ x,
                                            unsigned short* __restrict__ x_pk) {
  const int b = blockIdx.z, c0 = blockIdx.y * 64, n0 = blockIdx.x * 64;
  const int t = threadIdx.x;
  __shared__ unsigned short ts[64 * 72];  // [n][c]
  const int cl = t >> 2, nseg = (t & 3) * 16;
  const float* xr = x + ((size_t)b * C_ + c0 + cl) * N_ + n0 + nseg;
#pragma unroll
  for (int k = 0; k < 4; ++k) {
    float4 f = *(const float4*)(xr + k * 4);
    ts[(nseg + k * 4 + 0) * 72 + cl] = f2bf(f.x);
    ts[(nseg + k * 4 + 1) * 72 + cl] = f2bf(f.y);
    ts[(nseg + k * 4 + 2) * 72 + cl] = f2bf(f.z);
    ts[(nseg + k * 4 + 3) * 72 + cl] = f2bf(f.w);
  }
  __syncthreads();
  unsigned short* dst = x_pk + (size_t)b * N_ * C_;
#pragma unroll
  for (int u = t; u < 512; u += 256) {
    int blk = u >> 6, wi = (u & 63) * 8;
    int rl = (blk >> 1) * 16 + (wi >> 5);
    int kl = (blk & 1) * 32 + (wi & 31);
    int gr = n0 + rl, gk = c0 + kl;
    size_t go = ((size_t)(gr >> 4) * 16 + (gk >> 5)) * 512 + (gr & 15) * 32 + (gk & 31);
    *(int4*)&dst[go] = *(int4*)&ts[rl * 72 + kl];
  }
}

// ---------------------------------------------------------------------------
// K_qkv: y[o][n] = sum_c W[o][c] x[n][c] + b.  128o x 128n tile, 512 thr.
// ---------------------------------------------------------------------------
__global__ __launch_bounds__(512) void k_qkv(
    const unsigned short* __restrict__ w_pk, const unsigned short* __restrict__ x_pk,
    const float* __restrict__ bq, const float* __restrict__ bk, const float* __restrict__ bv,
    unsigned short* __restrict__ q_pk, unsigned short* __restrict__ k_pk,
    unsigned short* __restrict__ v_pk) {
  const int b = blockIdx.z, o0 = blockIdx.y * 128, n0 = blockIdx.x * 128;
  const int t = threadIdx.x, wave = t >> 6, lane = t & 63;
  const int la = lane & 15, quad = lane >> 4;
  const int ow = wave & 1, nw = wave >> 1;
  const int lanelin = la * 32 + quad * 8;
  const unsigned short* xpb = x_pk + (size_t)b * N_ * C_;
  __shared__ unsigned short tp[128 * 136];

  v4f acc[4][2];
#pragma unroll
  for (int i = 0; i < 4; ++i)
#pragma unroll
    for (int j = 0; j < 2; ++j) acc[i][j] = (v4f){0.f, 0.f, 0.f, 0.f};

  const int ar16 = (o0 + ow * 64) >> 4;
  const int br16 = (n0 + nw * 32) >> 4;
#pragma unroll 4
  for (int s = 0; s < 16; ++s) {
    v8s b0 = ld8(&xpb[((size_t)(br16 + 0) * 16 + s) * 512 + lanelin]);
    v8s b1 = ld8(&xpb[((size_t)(br16 + 1) * 16 + s) * 512 + lanelin]);
#pragma unroll
    for (int oi = 0; oi < 4; ++oi) {
      v8s a = ld8(&w_pk[((size_t)(ar16 + oi) * 16 + s) * 512 + lanelin]);
      acc[oi][0] = mfma16(a, b0, acc[oi][0]);
      acc[oi][1] = mfma16(a, b1, acc[oi][1]);
    }
  }

  if (o0 >= 512) {
#pragma unroll
    for (int oi = 0; oi < 4; ++oi)
#pragma unroll
      for (int nj = 0; nj < 2; ++nj)
#pragma unroll
        for (int r = 0; r < 4; ++r) {
          int cl = ow * 64 + oi * 16 + quad * 4 + r;
          int nl = nw * 32 + nj * 16 + la;
          tp[cl * 136 + nl] = f2bf(acc[oi][nj][r] + bv[o0 - 512 + cl]);
        }
    __syncthreads();
    unsigned short* dst = v_pk + (size_t)b * C_ * N_;
#pragma unroll
    for (int u = t; u < 2048; u += 512) {
      int blk = u >> 6, wi = (u & 63) * 8;
      int rl = (blk >> 2) * 16 + (wi >> 5);
      int kl = (blk & 3) * 32 + (wi & 31);
      int gr = (o0 - 512) + rl, gk = n0 + kl;
      size_t go = ((size_t)(gr >> 4) * 128 + (gk >> 5)) * 512 + (gr & 15) * 32 + (gk & 31);
      *(int4*)&dst[go] = *(int4*)&tp[rl * 136 + kl];
    }
  } else {
    const float* bias = (o0 < 256) ? bq : bk;
#pragma unroll
    for (int oi = 0; oi < 4; ++oi)
#pragma unroll
      for (int nj = 0; nj < 2; ++nj)
#pragma unroll
        for (int r = 0; r < 4; ++r) {
          int ol = ow * 64 + oi * 16 + quad * 4 + r;
          int nl = nw * 32 + nj * 16 + la;
          tp[nl * 136 + ol] = f2bf(acc[oi][nj][r] + bias[(o0 & 255) + ol]);
        }
    __syncthreads();
    unsigned short* dst = ((o0 < 256) ? q_pk : k_pk) + (size_t)b * N_ * CI_;
#pragma unroll
    for (int u = t; u < 2048; u += 512) {
      int blk = u >> 6, wi = (u & 63) * 8;
      int rl = (blk >> 2) * 16 + (wi >> 5);
      int kl = (blk & 3) * 32 + (wi & 31);
      int gr = n0 + rl, gk = (o0 & 255) + kl;
      size_t go = ((size_t)(gr >> 4) * 8 + (gk >> 5)) * 512 + (gr & 15) * 32 + (gk & 31);
      *(int4*)&dst[go] = *(int4*)&tp[rl * 136 + kl];
    }
  }
}

// ---------------------------------------------------------------------------
// K_pam v15 (verified best): v8 core loop, full j range, fused combine
// epilogue emitting sa_pk + saT_pk.
// ---------------------------------------------------------------------------
__device__ __forceinline__ void kstage(const unsigned short* g, unsigned short* l, int t) {
  __builtin_amdgcn_global_load_lds(
      (const __attribute__((address_space(1))) void*)(g + (size_t)t * 8),
      (__attribute__((address_space(3))) void*)(l + t * 8), 16, 0, 0);
  __builtin_amdgcn_global_load_lds(
      (const __attribute__((address_space(1))) void*)(g + 8192 + (size_t)t * 8),
      (__attribute__((address_space(3))) void*)(l + 8192 + t * 8), 16, 0, 0);
}

__global__ __launch_bounds__(1024) void k_pam(
    const unsigned short* __restrict__ q_pk, const unsigned short* __restrict__ k_pk,
    const unsigned short* __restrict__ v_pk, const float* __restrict__ x,
    const float* __restrict__ gamma_pam,
    unsigned short* __restrict__ sa_pk, unsigned short* __restrict__ saT_pk) {
  const int blk = blockIdx.x;
  const int b = blk & 3, i0 = (blk >> 2) * 64;
  const int t = threadIdx.x, wave = t >> 6, lane = t & 63;
  const int la = lane & 15, quad = lane >> 4;
  const int iw = wave & 3, jw = wave >> 2;
  const int cb = wave * 32;
  const int lanelin = la * 32 + quad * 8;

  __shared__ unsigned short kls[3][16384];  // 3 x 32KB K tiles; reused by epilogue
  __shared__ unsigned short pa[2][4096];    // 64x64 P, XOR-swizzled stride 64
  __shared__ float l_lds[64];
  if (t < 64) l_lds[t] = 0.f;

  const unsigned short* qpk = q_pk + (size_t)b * N_ * CI_;
  const unsigned short* kpk = k_pk + (size_t)b * N_ * CI_;
  const unsigned short* vpk = v_pk + (size_t)b * C_ * N_;

  v8s qf[8];
  {
    const unsigned short* qb = qpk + ((size_t)((i0 >> 4) + iw) * 8) * 512 + lanelin;
#pragma unroll
    for (int s = 0; s < 8; ++s) qf[s] = ld8(qb + s * 512);
  }

  v4f acc[2][4];  // [ct][it]
#pragma unroll
  for (int ct = 0; ct < 2; ++ct)
#pragma unroll
    for (int it = 0; it < 4; ++it) acc[ct][it] = (v4f){0.f, 0.f, 0.f, 0.f};
  float lsum[4] = {0.f, 0.f, 0.f, 0.f};

  // prologue: stage step0 -> kls[0], step1 -> kls[1]; drain step0 only.
  kstage(kpk, kls[0], t);
  kstage(kpk + (size_t)4 * 4096, kls[1], t);
  asm volatile("s_waitcnt vmcnt(2)" ::: "memory");  // DMA_0 done (in-order drain)
  __builtin_amdgcn_s_barrier();
  __builtin_amdgcn_sched_barrier(0);

  int pb = 0;
  for (int step = 0; step < 64; ++step) {
    const int j0 = step * 64;
    // phase 1: V frags (issued FIRST so PV waits vmcnt(2), not 0)
    v8s vf[2][2];
#pragma unroll
    for (int ct = 0; ct < 2; ++ct)
#pragma unroll
      for (int ks = 0; ks < 2; ++ks)
        vf[ct][ks] = ld8(&vpk[((size_t)((cb >> 4) + ct) * 128 + (j0 >> 5) + ks) * 512 + lanelin]);
    __builtin_amdgcn_sched_barrier(0);
    // phase 2: DMA K tile for step+2 into kls[(step+2)%3]
    int jn = j0 + 128; if (jn >= N_) jn = 0;  // tail clamp (data unused)
    kstage(kpk + (size_t)(jn >> 4) * 4096, kls[(step + 2) % 3], t);
    __builtin_amdgcn_sched_barrier(0);
    // phase 3: S = Q K^T from kls[step%3] (staged 2 steps ago; guaranteed by
    // previous step's vmcnt(6)+s_barrier)
    const unsigned short* kb = &kls[step % 3][jw * 4096 + lanelin];
    v4f sA = (v4f){0.f, 0.f, 0.f, 0.f}, sB = sA;
#pragma unroll
    for (int sh = 0; sh < 4; ++sh) {
      sA = mfma16(qf[sh], ld8(kb + sh * 512), sA);
      sB = mfma16(qf[sh + 4], ld8(kb + (sh + 4) * 512), sB);
    }
    // phase 4: P = exp(s*scale - shift), swizzled LDS write
#pragma unroll
    for (int r = 0; r < 4; ++r) {
      float p = __expf((sA[r] + sB[r]) * SCALE_PAM - SHIFT_PAM);
      lsum[r] += p;
      int row = iw * 16 + quad * 4 + r;
      pa[pb][((row << 6) + jw * 16 + la) ^ ((row & 7) << 3)] = f2bf(p);
    }
    // phase 5: fence. lgkmcnt(0): our P writes visible. vmcnt(6): drains the
    // 2 oldest vmem = DMA for step+1 (queue: DMA_{t+1}(2), V_t(4), DMA_{t+2}(2)).
    __builtin_amdgcn_sched_barrier(0);
    asm volatile("s_waitcnt lgkmcnt(0) vmcnt(6)" ::: "memory");
    __builtin_amdgcn_s_barrier();
    __builtin_amdgcn_sched_barrier(0);
    // phase 6: PV: acc[c][i] += V[c][j] * P[i][j]  (compiler waits vmcnt(2) for vf)
    __builtin_amdgcn_s_setprio(1);
#pragma unroll
    for (int it = 0; it < 4; ++it) {
      const int row = it * 16 + la;
      const int sw = (row & 7) << 3;
#pragma unroll
      for (int ks = 0; ks < 2; ++ks) {
        v8s pf; *(int4*)&pf = *(const int4*)&pa[pb][((row << 6) + ks * 32 + quad * 8) ^ sw];
#pragma unroll
        for (int ct = 0; ct < 2; ++ct)
          acc[ct][it] = mfma16(vf[ct][ks], pf, acc[ct][it]);
      }
    }
    __builtin_amdgcn_s_setprio(0);
    pb ^= 1;
  }

  // ---- fused k_combine epilogue ----
#pragma unroll
  for (int r = 0; r < 4; ++r) {
    float v = lsum[r];
    v += __shfl_xor(v, 1); v += __shfl_xor(v, 2);
    v += __shfl_xor(v, 4); v += __shfl_xor(v, 8);
    if (la == 0) atomicAdd(&l_lds[iw * 16 + quad * 4 + r], v);
  }
  __syncthreads();  // l complete; all waves past PV (kls free to reuse)

  const float gpv = gamma_pam[0];
  unsigned short* ts = &kls[0][0];  // stage 1: ts[c][72] (512*72 shorts = 73.7KB)
  unsigned short sv[2][4][4];
#pragma unroll
  for (int ct = 0; ct < 2; ++ct)
#pragma unroll
    for (int it = 0; it < 4; ++it) {
      const int nl = it * 16 + la;
      const float lv = l_lds[nl] * (float)N_;
#pragma unroll
      for (int r = 0; r < 4; ++r) {
        const int c = cb + ct * 16 + quad * 4 + r;
        const float xv = x[((size_t)b * C_ + c) * N_ + i0 + nl];
        const unsigned short h = f2bf(tanhf(fmaf(gpv, acc[ct][it][r] / lv, xv)));
        sv[ct][it][r] = h;
        ts[c * 72 + nl] = h;
      }
    }
  __syncthreads();
  {  // sa_pk: PK(512 c, 4096 n), row-block stride 128
    unsigned short* dst = sa_pk + (size_t)b * C_ * N_;
#pragma unroll
    for (int u = t; u < 4096; u += 1024) {
      int c = u >> 3, n8 = (u & 7) * 8;
      int gn = i0 + n8;
      size_t go = ((size_t)(c >> 4) * 128 + (gn >> 5)) * 512 + (c & 15) * 32 + (gn & 31);
      *(int4*)&dst[go] = *(const int4*)&ts[c * 72 + n8];
    }
  }
  __syncthreads();
  unsigned short* ts2 = &kls[0][0];  // stage 2: ts2[n][520] (64*520 = 66.6KB)
#pragma unroll
  for (int ct = 0; ct < 2; ++ct)
#pragma unroll
    for (int it = 0; it < 4; ++it)
#pragma unroll
      for (int r = 0; r < 4; ++r)
        ts2[(it * 16 + la) * 520 + (cb + ct * 16 + quad * 4 + r)] = sv[ct][it][r];
  __syncthreads();
  {  // saT_pk: PK(4096 n, 512 c), row-block stride 16
    unsigned short* dst = saT_pk + (size_t)b * N_ * C_;
#pragma unroll
    for (int u = t; u < 4096; u += 1024) {
      int nl = u >> 6, c8 = (u & 63) * 8;
      int gn = i0 + nl;
      size_t go = ((size_t)(gn >> 4) * 16 + (c8 >> 5)) * 512 + (gn & 15) * 32 + (c8 & 31);
      *(int4*)&dst[go] = *(const int4*)&ts2[nl * 520 + c8];
    }
  }
}

// ---------------------------------------------------------------------------
// K_cam_e v18: SYMMETRIC — e[c][d] = e[d][c], so compute only the upper
// triangle of the 8x8 tile grid (36 tiles vs 64, -44% MFMA+reads). Off-diag
// tiles emit the mirror tile via LDS transpose (stride-65 pad, coalesced
// copy-out). Reduction order per element unchanged -> bitwise-identical
// e_part. Grid (36, ks4, B). Softmax/cam_out unchanged (v15).
// ---------------------------------------------------------------------------
__global__ __launch_bounds__(256) void k_cam_e(const unsigned short* __restrict__ sa_pk,
                                               float* __restrict__ e_part) {
  const int b = blockIdx.z, ks = blockIdx.y;
  int idx = blockIdx.x;  // 0..35 -> (ci,di), ci <= di
  int ci = 0;
  while (idx >= 8 - ci) { idx -= 8 - ci; ++ci; }
  const int di = ci + idx;
  const int c0 = ci * 64, d0 = di * 64;
  const int t = threadIdx.x, wave = t >> 6, lane = t & 63;
  const int la = lane & 15, quad = lane >> 4;
  const int cw = wave & 1, dw = wave >> 1;
  const int lanelin = la * 32 + quad * 8;
  const unsigned short* sb = sa_pk + (size_t)b * C_ * N_;
  __shared__ float tr[64 * 65];

  v4f acc[2][2];
#pragma unroll
  for (int i = 0; i < 2; ++i)
#pragma unroll
    for (int j = 0; j < 2; ++j) acc[i][j] = (v4f){0.f, 0.f, 0.f, 0.f};

  const int ar16 = (c0 + cw * 32) >> 4;
  const int br16 = (d0 + dw * 32) >> 4;
#pragma unroll 4
  for (int s = 0; s < 32; ++s) {
    const int k32 = ks * 32 + s;
    v8s a0 = ld8(&sb[((size_t)(ar16 + 0) * 128 + k32) * 512 + lanelin]);
    v8s a1 = ld8(&sb[((size_t)(ar16 + 1) * 128 + k32) * 512 + lanelin]);
    v8s b0 = ld8(&sb[((size_t)(br16 + 0) * 128 + k32) * 512 + lanelin]);
    v8s b1 = ld8(&sb[((size_t)(br16 + 1) * 128 + k32) * 512 + lanelin]);
    acc[0][0] = mfma16(a0, b0, acc[0][0]);
    acc[0][1] = mfma16(a0, b1, acc[0][1]);
    acc[1][0] = mfma16(a1, b0, acc[1][0]);
    acc[1][1] = mfma16(a1, b1, acc[1][1]);
  }
  float* ep = e_part + ((size_t)(ks * B_ + b)) * C_ * C_;
#pragma unroll
  for (int i = 0; i < 2; ++i)
#pragma unroll
    for (int j = 0; j < 2; ++j)
#pragma unroll
      for (int r = 0; r < 4; ++r) {
        int cl = cw * 32 + i * 16 + quad * 4 + r;
        int dl = dw * 32 + j * 16 + la;
        float v = acc[i][j][r] * SCALE_CAM;
        ep[(size_t)(c0 + cl) * C_ + d0 + dl] = v;
        tr[dl * 65 + cl] = v;
      }
  if (ci != di) {  // mirror tile (block-uniform branch)
    __syncthreads();
#pragma unroll
    for (int u = t; u < 4096; u += 256) {
      int dl = u >> 6, cl = u & 63;
      ep[(size_t)(d0 + dl) * C_ + c0 + cl] = tr[dl * 65 + cl];
    }
  }
}

// ---------------------------------------------------------------------------
// K_cam_softmax: min-trick softmax over 4 parts -> attn_pk PK(512,512).
// ---------------------------------------------------------------------------
__global__ __launch_bounds__(64) void k_cam_softmax(const float* __restrict__ e_part,
                                                    unsigned short* __restrict__ attn_pk) {
  const int c = blockIdx.x, b = blockIdx.y, lane = threadIdx.x;
  size_t roff = ((size_t)b * C_ + c) * C_;
  float vals[8];
#pragma unroll
  for (int r = 0; r < 8; ++r) {
    int d = lane + r * 64;
    float s = 0.f;
#pragma unroll
    for (int p = 0; p < 4; ++p) s += e_part[(size_t)(p * B_) * C_ * C_ + roff + d];
    vals[r] = s;
  }
  float mn = vals[0];
#pragma unroll
  for (int r = 1; r < 8; ++r) mn = fminf(mn, vals[r]);
#pragma unroll
  for (int m = 32; m >= 1; m >>= 1) mn = fminf(mn, __shfl_xor(mn, m));
  float sum = 0.f;
#pragma unroll
  for (int r = 0; r < 8; ++r) { vals[r] = __expf(mn - vals[r]); sum += vals[r]; }
#pragma unroll
  for (int m = 32; m >= 1; m >>= 1) sum += __shfl_xor(sum, m);
  float sc = (1.0f / (float)C_) / sum;
  unsigned short* ab = attn_pk + (size_t)b * C_ * C_;
#pragma unroll
  for (int r = 0; r < 8; ++r) {
    int d = lane + r * 64;
    size_t go = ((size_t)(c >> 4) * 16 + (d >> 5)) * 512 + (c & 15) * 32 + (d & 31);
    ab[go] = f2bf(vals[r] * sc);
  }
}

// ---------------------------------------------------------------------------
// K_cam_out: out = gc * (attn @ sa) + sa.  128c x 128n tile, 512 thr.
// ---------------------------------------------------------------------------
__global__ __launch_bounds__(512) void k_cam_out(
    const unsigned short* __restrict__ attn_pk, const unsigned short* __restrict__ saT_pk,
    const unsigned short* __restrict__ sa_pk, const float* __restrict__ gamma_cam,
    float* __restrict__ out) {
  const int b = blockIdx.z, c0 = blockIdx.y * 128, n0 = blockIdx.x * 128;
  const int t = threadIdx.x, wave = t >> 6, lane = t & 63;
  const int la = lane & 15, quad = lane >> 4;
  const int cw = wave & 1, nw = wave >> 1;
  const int lanelin = la * 32 + quad * 8;
  const unsigned short* ab = attn_pk + (size_t)b * C_ * C_;
  const unsigned short* sTb = saT_pk + (size_t)b * N_ * C_;
  const unsigned short* sb = sa_pk + (size_t)b * C_ * N_;

  v4f acc[4][2];
#pragma unroll
  for (int i = 0; i < 4; ++i)
#pragma unroll
    for (int j = 0; j < 2; ++j) acc[i][j] = (v4f){0.f, 0.f, 0.f, 0.f};

  const int ar16 = (c0 + cw * 64) >> 4;
  const int br16 = (n0 + nw * 32) >> 4;
#pragma unroll 4
  for (int s = 0; s < 16; ++s) {
    v8s b0 = ld8(&sTb[((size_t)(br16 + 0) * 16 + s) * 512 + lanelin]);
    v8s b1 = ld8(&sTb[((size_t)(br16 + 1) * 16 + s) * 512 + lanelin]);
#pragma unroll
    for (int ci = 0; ci < 4; ++ci) {
      v8s a = ld8(&ab[((size_t)(ar16 + ci) * 16 + s) * 512 + lanelin]);
      acc[ci][0] = mfma16(a, b0, acc[ci][0]);
      acc[ci][1] = mfma16(a, b1, acc[ci][1]);
    }
  }
  const float gc = gamma_cam[0];
#pragma unroll
  for (int ci = 0; ci < 4; ++ci)
#pragma unroll
    for (int nj = 0; nj < 2; ++nj)
#pragma unroll
      for (int r = 0; r < 4; ++r) {
        int c = c0 + cw * 64 + ci * 16 + quad * 4 + r;
        int n = n0 + nw * 32 + nj * 16 + la;
        size_t pko = ((size_t)(c >> 4) * 128 + (n >> 5)) * 512 + (c & 15) * 32 + (n & 31);
        out[((size_t)b * C_ + c) * N_ + n] = fmaf(gc, acc[ci][nj][r], bf2f(sb[pko]));
      }
}

// ---------------------------------------------------------------------------
extern "C" void kernel_launch(void* const* d_in, const int* in_sizes, int n_in,
                              void* d_out, int out_size, void* d_ws, size_t ws_size,
                              hipStream_t stream) {
  const float* x  = (const float*)d_in[0];
  const float* wq = (const float*)d_in[1];
  const float* bq = (const float*)d_in[2];
  const float* wk = (const float*)d_in[3];
  const float* bk = (const float*)d_in[4];
  const float* wv = (const float*)d_in[5];
  const float* bv = (const float*)d_in[6];
  const float* gp = (const float*)d_in[7];
  const float* gc = (const float*)d_in[8];
  float* out = (float*)d_out;

  char* ws = (char*)d_ws;
  // Region map (k_combine fused into k_pam; max used = 84.9 MB):
  //  A 0        : x_pk (16.78M)   -> later at_pk (2.1M)
  //  B 16.78M   : w_pk (1.05M)
  //  C 17.83M   : q_pk (8.39M)    (live through k_pam)
  //  D 26.21M   : k_pk (8.39M)    (live through k_pam)
  //  E 34.60M   : v_pk (16.78M)   -> later ep (16.78M)
  //  F 51.38M   : sa_pk (16.78M)
  //  G 68.16M   : saT_pk (16.78M)
  unsigned short* x_pk   = (unsigned short*)(ws);
  unsigned short* w_pk   = (unsigned short*)(ws + 16777216);
  unsigned short* q_pk   = (unsigned short*)(ws + 17825792);
  unsigned short* k_pk   = (unsigned short*)(ws + 26214400);
  unsigned short* v_pk   = (unsigned short*)(ws + 34603008);
  unsigned short* sa_pk  = (unsigned short*)(ws + 51380224);
  unsigned short* saT_pk = (unsigned short*)(ws + 68157440);
  float*          ep     = (float*)(ws + 34603008);            // reuse E
  unsigned short* at_pk  = (unsigned short*)(ws);              // reuse A

  k_xT<<<dim3(64, 8, B_), 256, 0, stream>>>(x, x_pk);
  k_wb<<<256, 256, 0, stream>>>(wq, wk, wv, w_pk);
  k_qkv<<<dim3(32, 8, B_), 512, 0, stream>>>(w_pk, x_pk, bq, bk, bv, q_pk, k_pk, v_pk);
  k_pam<<<256, 1024, 0, stream>>>(q_pk, k_pk, v_pk, x, gp, sa_pk, saT_pk);
  k_cam_e<<<dim3(36, 4, B_), 256, 0, stream>>>(sa_pk, ep);
  k_cam_softmax<<<dim3(C_, B_), 64, 0, stream>>>(ep, at_pk);
  k_cam_out<<<dim3(32, 4, B_), 512, 0, stream>>>(at_pk, saT_pk, sa_pk, gc, out);
}

// Round 16
// 357.174 us; speedup vs baseline: 1.0442x; 1.0029x over previous
//
#include <hip/hip_runtime.h>

#define B_ 4
#define C_ 512
#define CI_ 256
#define N_ 4096
#define SCALE_PAM 0.04419417382415922f  // 1/sqrt(512)
#define SCALE_CAM (1.0f/64.0f)          // 1/sqrt(4096)
#define SHIFT_PAM 8.0f

typedef float v4f __attribute__((ext_vector_type(4)));
typedef short v8s __attribute__((ext_vector_type(8)));

__device__ __forceinline__ unsigned short f2bf(float f) {
  unsigned int u = __float_as_uint(f);
  u = (u + 0x7FFFu + ((u >> 16) & 1u)) >> 16;
  return (unsigned short)u;
}
__device__ __forceinline__ float bf2f(unsigned short s) {
  return __uint_as_float(((unsigned int)s) << 16);
}
__device__ __forceinline__ v8s ld8(const unsigned short* p) {
  v8s r; *(int4*)&r = *(const int4*)p; return r;
}
__device__ __forceinline__ v4f mfma16(v8s a, v8s b, v4f c) {
  return __builtin_amdgcn_mfma_f32_16x16x32_bf16(a, b, c, 0, 0, 0);
}
// PK layout: off(r,k) = ((r>>4)*(K>>5) + (k>>5))*512 + (r&15)*32 + (k&31)  [shorts]
// Wave frag load: base + lanelin, lanelin=(lane&15)*32+(lane>>4)*8 -> contiguous 1KB.

// ---------------------------------------------------------------------------
// K_prep: fused k_xT + k_wb (independent work, one launch).
//  blocks [0,2048): x fp32 [b][c][n] -> x_pk PK(4096,512) per batch.
//  blocks [2048,2304): wq/wk/wv fp32 -> w_pk PK(1024,512).
// Branch is block-uniform -> LDS barrier in the xT path is safe.
// ---------------------------------------------------------------------------
__global__ __launch_bounds__(256) void k_prep(const float* __restrict__ x,
                                              const float* __restrict__ wq,
                                              const float* __restrict__ wk,
                                              const float* __restrict__ wv,
                                              unsigned short* __restrict__ x_pk,
                                              unsigned short* __restrict__ w_pk) {
  const int t = threadIdx.x;
  if (blockIdx.x >= 2048) {  // ---- wb part ----
    int u = (blockIdx.x - 2048) * 256 + t;
    int blk = u >> 6, wi = (u & 63) * 8;
    int r = (blk >> 4) * 16 + (wi >> 5);
    int k = (blk & 15) * 32 + (wi & 31);
    const float* src = (r < 256) ? &wq[r * 512 + k]
                     : (r < 512) ? &wk[(r - 256) * 512 + k]
                                 : &wv[(r - 512) * 512 + k];
    float4 f0 = *(const float4*)src, f1 = *(const float4*)(src + 4);
    ushort4 o0 = { f2bf(f0.x), f2bf(f0.y), f2bf(f0.z), f2bf(f0.w) };
    ushort4 o1 = { f2bf(f1.x), f2bf(f1.y), f2bf(f1.z), f2bf(f1.w) };
    *(ushort4*)&w_pk[u * 8] = o0;
    *(ushort4*)&w_pk[u * 8 + 4] = o1;
    return;
  }
  // ---- xT part ----
  const int b = blockIdx.x >> 9, c0 = ((blockIdx.x >> 6) & 7) * 64, n0 = (blockIdx.x & 63) * 64;
  __shared__ unsigned short ts[64 * 72];  // [n][c]
  const int cl = t >> 2, nseg = (t & 3) * 16;
  const float* xr = x + ((size_t)b * C_ + c0 + cl) * N_ + n0 + nseg;
#pragma unroll
  for (int k = 0; k < 4; ++k) {
    float4 f = *(const float4*)(xr + k * 4);
    ts[(nseg + k * 4 + 0) * 72 + cl] = f2bf(f.x);
    ts[(nseg + k * 4 + 1) * 72 + cl] = f2bf(f.y);
    ts[(nseg + k * 4 + 2) * 72 + cl] = f2bf(f.z);
    ts[(nseg + k * 4 + 3) * 72 + cl] = f2bf(f.w);
  }
  __syncthreads();
  unsigned short* dst = x_pk + (size_t)b * N_ * C_;
#pragma unroll
  for (int u = t; u < 512; u += 256) {
    int blk = u >> 6, wi = (u & 63) * 8;
    int rl = (blk >> 1) * 16 + (wi >> 5);
    int kl = (blk & 1) * 32 + (wi & 31);
    int gr = n0 + rl, gk = c0 + kl;
    size_t go = ((size_t)(gr >> 4) * 16 + (gk >> 5)) * 512 + (gr & 15) * 32 + (gk & 31);
    *(int4*)&dst[go] = *(int4*)&ts[rl * 72 + kl];
  }
}

// ---------------------------------------------------------------------------
// K_qkv: y[o][n] = sum_c W[o][c] x[n][c] + b.  128o x 128n tile, 512 thr.
// ---------------------------------------------------------------------------
__global__ __launch_bounds__(512) void k_qkv(
    const unsigned short* __restrict__ w_pk, const unsigned short* __restrict__ x_pk,
    const float* __restrict__ bq, const float* __restrict__ bk, const float* __restrict__ bv,
    unsigned short* __restrict__ q_pk, unsigned short* __restrict__ k_pk,
    unsigned short* __restrict__ v_pk) {
  const int b = blockIdx.z, o0 = blockIdx.y * 128, n0 = blockIdx.x * 128;
  const int t = threadIdx.x, wave = t >> 6, lane = t & 63;
  const int la = lane & 15, quad = lane >> 4;
  const int ow = wave & 1, nw = wave >> 1;
  const int lanelin = la * 32 + quad * 8;
  const unsigned short* xpb = x_pk + (size_t)b * N_ * C_;
  __shared__ unsigned short tp[128 * 136];

  v4f acc[4][2];
#pragma unroll
  for (int i = 0; i < 4; ++i)
#pragma unroll
    for (int j = 0; j < 2; ++j) acc[i][j] = (v4f){0.f, 0.f, 0.f, 0.f};

  const int ar16 = (o0 + ow * 64) >> 4;
  const int br16 = (n0 + nw * 32) >> 4;
#pragma unroll 4
  for (int s = 0; s < 16; ++s) {
    v8s b0 = ld8(&xpb[((size_t)(br16 + 0) * 16 + s) * 512 + lanelin]);
    v8s b1 = ld8(&xpb[((size_t)(br16 + 1) * 16 + s) * 512 + lanelin]);
#pragma unroll
    for (int oi = 0; oi < 4; ++oi) {
      v8s a = ld8(&w_pk[((size_t)(ar16 + oi) * 16 + s) * 512 + lanelin]);
      acc[oi][0] = mfma16(a, b0, acc[oi][0]);
      acc[oi][1] = mfma16(a, b1, acc[oi][1]);
    }
  }

  if (o0 >= 512) {
#pragma unroll
    for (int oi = 0; oi < 4; ++oi)
#pragma unroll
      for (int nj = 0; nj < 2; ++nj)
#pragma unroll
        for (int r = 0; r < 4; ++r) {
          int cl = ow * 64 + oi * 16 + quad * 4 + r;
          int nl = nw * 32 + nj * 16 + la;
          tp[cl * 136 + nl] = f2bf(acc[oi][nj][r] + bv[o0 - 512 + cl]);
        }
    __syncthreads();
    unsigned short* dst = v_pk + (size_t)b * C_ * N_;
#pragma unroll
    for (int u = t; u < 2048; u += 512) {
      int blk = u >> 6, wi = (u & 63) * 8;
      int rl = (blk >> 2) * 16 + (wi >> 5);
      int kl = (blk & 3) * 32 + (wi & 31);
      int gr = (o0 - 512) + rl, gk = n0 + kl;
      size_t go = ((size_t)(gr >> 4) * 128 + (gk >> 5)) * 512 + (gr & 15) * 32 + (gk & 31);
      *(int4*)&dst[go] = *(int4*)&tp[rl * 136 + kl];
    }
  } else {
    const float* bias = (o0 < 256) ? bq : bk;
#pragma unroll
    for (int oi = 0; oi < 4; ++oi)
#pragma unroll
      for (int nj = 0; nj < 2; ++nj)
#pragma unroll
        for (int r = 0; r < 4; ++r) {
          int ol = ow * 64 + oi * 16 + quad * 4 + r;
          int nl = nw * 32 + nj * 16 + la;
          tp[nl * 136 + ol] = f2bf(acc[oi][nj][r] + bias[(o0 & 255) + ol]);
        }
    __syncthreads();
    unsigned short* dst = ((o0 < 256) ? q_pk : k_pk) + (size_t)b * N_ * CI_;
#pragma unroll
    for (int u = t; u < 2048; u += 512) {
      int blk = u >> 6, wi = (u & 63) * 8;
      int rl = (blk >> 2) * 16 + (wi >> 5);
      int kl = (blk & 3) * 32 + (wi & 31);
      int gr = n0 + rl, gk = (o0 & 255) + kl;
      size_t go = ((size_t)(gr >> 4) * 8 + (gk >> 5)) * 512 + (gr & 15) * 32 + (gk & 31);
      *(int4*)&dst[go] = *(int4*)&tp[rl * 136 + kl];
    }
  }
}

// ---------------------------------------------------------------------------
// K_pam v15 (verified best): v8 core loop, full j range, fused combine
// epilogue emitting sa_pk + saT_pk.
// ---------------------------------------------------------------------------
__device__ __forceinline__ void kstage(const unsigned short* g, unsigned short* l, int t) {
  __builtin_amdgcn_global_load_lds(
      (const __attribute__((address_space(1))) void*)(g + (size_t)t * 8),
      (__attribute__((address_space(3))) void*)(l + t * 8), 16, 0, 0);
  __builtin_amdgcn_global_load_lds(
      (const __attribute__((address_space(1))) void*)(g + 8192 + (size_t)t * 8),
      (__attribute__((address_space(3))) void*)(l + 8192 + t * 8), 16, 0, 0);
}

__global__ __launch_bounds__(1024) void k_pam(
    const unsigned short* __restrict__ q_pk, const unsigned short* __restrict__ k_pk,
    const unsigned short* __restrict__ v_pk, const float* __restrict__ x,
    const float* __restrict__ gamma_pam,
    unsigned short* __restrict__ sa_pk, unsigned short* __restrict__ saT_pk) {
  const int blk = blockIdx.x;
  const int b = blk & 3, i0 = (blk >> 2) * 64;
  const int t = threadIdx.x, wave = t >> 6, lane = t & 63;
  const int la = lane & 15, quad = lane >> 4;
  const int iw = wave & 3, jw = wave >> 2;
  const int cb = wave * 32;
  const int lanelin = la * 32 + quad * 8;

  __shared__ unsigned short kls[3][16384];  // 3 x 32KB K tiles; reused by epilogue
  __shared__ unsigned short pa[2][4096];    // 64x64 P, XOR-swizzled stride 64
  __shared__ float l_lds[64];
  if (t < 64) l_lds[t] = 0.f;

  const unsigned short* qpk = q_pk + (size_t)b * N_ * CI_;
  const unsigned short* kpk = k_pk + (size_t)b * N_ * CI_;
  const unsigned short* vpk = v_pk + (size_t)b * C_ * N_;

  v8s qf[8];
  {
    const unsigned short* qb = qpk + ((size_t)((i0 >> 4) + iw) * 8) * 512 + lanelin;
#pragma unroll
    for (int s = 0; s < 8; ++s) qf[s] = ld8(qb + s * 512);
  }

  v4f acc[2][4];  // [ct][it]
#pragma unroll
  for (int ct = 0; ct < 2; ++ct)
#pragma unroll
    for (int it = 0; it < 4; ++it) acc[ct][it] = (v4f){0.f, 0.f, 0.f, 0.f};
  float lsum[4] = {0.f, 0.f, 0.f, 0.f};

  // prologue: stage step0 -> kls[0], step1 -> kls[1]; drain step0 only.
  kstage(kpk, kls[0], t);
  kstage(kpk + (size_t)4 * 4096, kls[1], t);
  asm volatile("s_waitcnt vmcnt(2)" ::: "memory");  // DMA_0 done (in-order drain)
  __builtin_amdgcn_s_barrier();
  __builtin_amdgcn_sched_barrier(0);

  int pb = 0;
  for (int step = 0; step < 64; ++step) {
    const int j0 = step * 64;
    // phase 1: V frags (issued FIRST so PV waits vmcnt(2), not 0)
    v8s vf[2][2];
#pragma unroll
    for (int ct = 0; ct < 2; ++ct)
#pragma unroll
      for (int ks = 0; ks < 2; ++ks)
        vf[ct][ks] = ld8(&vpk[((size_t)((cb >> 4) + ct) * 128 + (j0 >> 5) + ks) * 512 + lanelin]);
    __builtin_amdgcn_sched_barrier(0);
    // phase 2: DMA K tile for step+2 into kls[(step+2)%3]
    int jn = j0 + 128; if (jn >= N_) jn = 0;  // tail clamp (data unused)
    kstage(kpk + (size_t)(jn >> 4) * 4096, kls[(step + 2) % 3], t);
    __builtin_amdgcn_sched_barrier(0);
    // phase 3: S = Q K^T from kls[step%3] (staged 2 steps ago; guaranteed by
    // previous step's vmcnt(6)+s_barrier)
    const unsigned short* kb = &kls[step % 3][jw * 4096 + lanelin];
    v4f sA = (v4f){0.f, 0.f, 0.f, 0.f}, sB = sA;
#pragma unroll
    for (int sh = 0; sh < 4; ++sh) {
      sA = mfma16(qf[sh], ld8(kb + sh * 512), sA);
      sB = mfma16(qf[sh + 4], ld8(kb + (sh + 4) * 512), sB);
    }
    // phase 4: P = exp(s*scale - shift), swizzled LDS write
#pragma unroll
    for (int r = 0; r < 4; ++r) {
      float p = __expf((sA[r] + sB[r]) * SCALE_PAM - SHIFT_PAM);
      lsum[r] += p;
      int row = iw * 16 + quad * 4 + r;
      pa[pb][((row << 6) + jw * 16 + la) ^ ((row & 7) << 3)] = f2bf(p);
    }
    // phase 5: fence. lgkmcnt(0): our P writes visible. vmcnt(6): drains the
    // 2 oldest vmem = DMA for step+1 (queue: DMA_{t+1}(2), V_t(4), DMA_{t+2}(2)).
    __builtin_amdgcn_sched_barrier(0);
    asm volatile("s_waitcnt lgkmcnt(0) vmcnt(6)" ::: "memory");
    __builtin_amdgcn_s_barrier();
    __builtin_amdgcn_sched_barrier(0);
    // phase 6: PV: acc[c][i] += V[c][j] * P[i][j]  (compiler waits vmcnt(2) for vf)
    __builtin_amdgcn_s_setprio(1);
#pragma unroll
    for (int it = 0; it < 4; ++it) {
      const int row = it * 16 + la;
      const int sw = (row & 7) << 3;
#pragma unroll
      for (int ks = 0; ks < 2; ++ks) {
        v8s pf; *(int4*)&pf = *(const int4*)&pa[pb][((row << 6) + ks * 32 + quad * 8) ^ sw];
#pragma unroll
        for (int ct = 0; ct < 2; ++ct)
          acc[ct][it] = mfma16(vf[ct][ks], pf, acc[ct][it]);
      }
    }
    __builtin_amdgcn_s_setprio(0);
    pb ^= 1;
  }

  // ---- fused k_combine epilogue ----
#pragma unroll
  for (int r = 0; r < 4; ++r) {
    float v = lsum[r];
    v += __shfl_xor(v, 1); v += __shfl_xor(v, 2);
    v += __shfl_xor(v, 4); v += __shfl_xor(v, 8);
    if (la == 0) atomicAdd(&l_lds[iw * 16 + quad * 4 + r], v);
  }
  __syncthreads();  // l complete; all waves past PV (kls free to reuse)

  const float gpv = gamma_pam[0];
  unsigned short* ts = &kls[0][0];  // stage 1: ts[c][72] (512*72 shorts = 73.7KB)
  unsigned short sv[2][4][4];
#pragma unroll
  for (int ct = 0; ct < 2; ++ct)
#pragma unroll
    for (int it = 0; it < 4; ++it) {
      const int nl = it * 16 + la;
      const float lv = l_lds[nl] * (float)N_;
#pragma unroll
      for (int r = 0; r < 4; ++r) {
        const int c = cb + ct * 16 + quad * 4 + r;
        const float xv = x[((size_t)b * C_ + c) * N_ + i0 + nl];
        const unsigned short h = f2bf(tanhf(fmaf(gpv, acc[ct][it][r] / lv, xv)));
        sv[ct][it][r] = h;
        ts[c * 72 + nl] = h;
      }
    }
  __syncthreads();
  {  // sa_pk: PK(512 c, 4096 n), row-block stride 128
    unsigned short* dst = sa_pk + (size_t)b * C_ * N_;
#pragma unroll
    for (int u = t; u < 4096; u += 1024) {
      int c = u >> 3, n8 = (u & 7) * 8;
      int gn = i0 + n8;
      size_t go = ((size_t)(c >> 4) * 128 + (gn >> 5)) * 512 + (c & 15) * 32 + (gn & 31);
      *(int4*)&dst[go] = *(const int4*)&ts[c * 72 + n8];
    }
  }
  __syncthreads();
  unsigned short* ts2 = &kls[0][0];  // stage 2: ts2[n][520] (64*520 = 66.6KB)
#pragma unroll
  for (int ct = 0; ct < 2; ++ct)
#pragma unroll
    for (int it = 0; it < 4; ++it)
#pragma unroll
      for (int r = 0; r < 4; ++r)
        ts2[(it * 16 + la) * 520 + (cb + ct * 16 + quad * 4 + r)] = sv[ct][it][r];
  __syncthreads();
  {  // saT_pk: PK(4096 n, 512 c), row-block stride 16
    unsigned short* dst = saT_pk + (size_t)b * N_ * C_;
#pragma unroll
    for (int u = t; u < 4096; u += 1024) {
      int nl = u >> 6, c8 = (u & 63) * 8;
      int gn = i0 + nl;
      size_t go = ((size_t)(gn >> 4) * 16 + (c8 >> 5)) * 512 + (gn & 15) * 32 + (c8 & 31);
      *(int4*)&dst[go] = *(const int4*)&ts2[nl * 520 + c8];
    }
  }
}

// ---------------------------------------------------------------------------
// K_cam_e v18: SYMMETRIC — compute upper-triangle tiles only (36 of 64);
// off-diag tiles mirror via LDS transpose. Bitwise-identical e_part.
// ---------------------------------------------------------------------------
__global__ __launch_bounds__(256) void k_cam_e(const unsigned short* __restrict__ sa_pk,
                                               float* __restrict__ e_part) {
  const int b = blockIdx.z, ks = blockIdx.y;
  int idx = blockIdx.x;  // 0..35 -> (ci,di), ci <= di
  int ci = 0;
  while (idx >= 8 - ci) { idx -= 8 - ci; ++ci; }
  const int di = ci + idx;
  const int c0 = ci * 64, d0 = di * 64;
  const int t = threadIdx.x, wave = t >> 6, lane = t & 63;
  const int la = lane & 15, quad = lane >> 4;
  const int cw = wave & 1, dw = wave >> 1;
  const int lanelin = la * 32 + quad * 8;
  const unsigned short* sb = sa_pk + (size_t)b * C_ * N_;
  __shared__ float tr[64 * 65];

  v4f acc[2][2];
#pragma unroll
  for (int i = 0; i < 2; ++i)
#pragma unroll
    for (int j = 0; j < 2; ++j) acc[i][j] = (v4f){0.f, 0.f, 0.f, 0.f};

  const int ar16 = (c0 + cw * 32) >> 4;
  const int br16 = (d0 + dw * 32) >> 4;
#pragma unroll 4
  for (int s = 0; s < 32; ++s) {
    const int k32 = ks * 32 + s;
    v8s a0 = ld8(&sb[((size_t)(ar16 + 0) * 128 + k32) * 512 + lanelin]);
    v8s a1 = ld8(&sb[((size_t)(ar16 + 1) * 128 + k32) * 512 + lanelin]);
    v8s b0 = ld8(&sb[((size_t)(br16 + 0) * 128 + k32) * 512 + lanelin]);
    v8s b1 = ld8(&sb[((size_t)(br16 + 1) * 128 + k32) * 512 + lanelin]);
    acc[0][0] = mfma16(a0, b0, acc[0][0]);
    acc[0][1] = mfma16(a0, b1, acc[0][1]);
    acc[1][0] = mfma16(a1, b0, acc[1][0]);
    acc[1][1] = mfma16(a1, b1, acc[1][1]);
  }
  float* ep = e_part + ((size_t)(ks * B_ + b)) * C_ * C_;
#pragma unroll
  for (int i = 0; i < 2; ++i)
#pragma unroll
    for (int j = 0; j < 2; ++j)
#pragma unroll
      for (int r = 0; r < 4; ++r) {
        int cl = cw * 32 + i * 16 + quad * 4 + r;
        int dl = dw * 32 + j * 16 + la;
        float v = acc[i][j][r] * SCALE_CAM;
        ep[(size_t)(c0 + cl) * C_ + d0 + dl] = v;
        tr[dl * 65 + cl] = v;
      }
  if (ci != di) {  // mirror tile (block-uniform branch)
    __syncthreads();
#pragma unroll
    for (int u = t; u < 4096; u += 256) {
      int dl = u >> 6, cl = u & 63;
      ep[(size_t)(d0 + dl) * C_ + c0 + cl] = tr[dl * 65 + cl];
    }
  }
}

// ---------------------------------------------------------------------------
// K_cam_softmax: min-trick softmax over 4 parts -> attn_pk PK(512,512).
// ---------------------------------------------------------------------------
__global__ __launch_bounds__(64) void k_cam_softmax(const float* __restrict__ e_part,
                                                    unsigned short* __restrict__ attn_pk) {
  const int c = blockIdx.x, b = blockIdx.y, lane = threadIdx.x;
  size_t roff = ((size_t)b * C_ + c) * C_;
  float vals[8];
#pragma unroll
  for (int r = 0; r < 8; ++r) {
    int d = lane + r * 64;
    float s = 0.f;
#pragma unroll
    for (int p = 0; p < 4; ++p) s += e_part[(size_t)(p * B_) * C_ * C_ + roff + d];
    vals[r] = s;
  }
  float mn = vals[0];
#pragma unroll
  for (int r = 1; r < 8; ++r) mn = fminf(mn, vals[r]);
#pragma unroll
  for (int m = 32; m >= 1; m >>= 1) mn = fminf(mn, __shfl_xor(mn, m));
  float sum = 0.f;
#pragma unroll
  for (int r = 0; r < 8; ++r) { vals[r] = __expf(mn - vals[r]); sum += vals[r]; }
#pragma unroll
  for (int m = 32; m >= 1; m >>= 1) sum += __shfl_xor(sum, m);
  float sc = (1.0f / (float)C_) / sum;
  unsigned short* ab = attn_pk + (size_t)b * C_ * C_;
#pragma unroll
  for (int r = 0; r < 8; ++r) {
    int d = lane + r * 64;
    size_t go = ((size_t)(c >> 4) * 16 + (d >> 5)) * 512 + (c & 15) * 32 + (d & 31);
    ab[go] = f2bf(vals[r] * sc);
  }
}

// ---------------------------------------------------------------------------
// K_cam_out: out = gc * (attn @ sa) + sa.  128c x 128n tile, 512 thr.
// ---------------------------------------------------------------------------
__global__ __launch_bounds__(512) void k_cam_out(
    const unsigned short* __restrict__ attn_pk, const unsigned short* __restrict__ saT_pk,
    const unsigned short* __restrict__ sa_pk, const float* __restrict__ gamma_cam,
    float* __restrict__ out) {
  const int b = blockIdx.z, c0 = blockIdx.y * 128, n0 = blockIdx.x * 128;
  const int t = threadIdx.x, wave = t >> 6, lane = t & 63;
  const int la = lane & 15, quad = lane >> 4;
  const int cw = wave & 1, nw = wave >> 1;
  const int lanelin = la * 32 + quad * 8;
  const unsigned short* ab = attn_pk + (size_t)b * C_ * C_;
  const unsigned short* sTb = saT_pk + (size_t)b * N_ * C_;
  const unsigned short* sb = sa_pk + (size_t)b * C_ * N_;

  v4f acc[4][2];
#pragma unroll
  for (int i = 0; i < 4; ++i)
#pragma unroll
    for (int j = 0; j < 2; ++j) acc[i][j] = (v4f){0.f, 0.f, 0.f, 0.f};

  const int ar16 = (c0 + cw * 64) >> 4;
  const int br16 = (n0 + nw * 32) >> 4;
#pragma unroll 4
  for (int s = 0; s < 16; ++s) {
    v8s b0 = ld8(&sTb[((size_t)(br16 + 0) * 16 + s) * 512 + lanelin]);
    v8s b1 = ld8(&sTb[((size_t)(br16 + 1) * 16 + s) * 512 + lanelin]);
#pragma unroll
    for (int ci = 0; ci < 4; ++ci) {
      v8s a = ld8(&ab[((size_t)(ar16 + ci) * 16 + s) * 512 + lanelin]);
      acc[ci][0] = mfma16(a, b0, acc[ci][0]);
      acc[ci][1] = mfma16(a, b1, acc[ci][1]);
    }
  }
  const float gc = gamma_cam[0];
#pragma unroll
  for (int ci = 0; ci < 4; ++ci)
#pragma unroll
    for (int nj = 0; nj < 2; ++nj)
#pragma unroll
      for (int r = 0; r < 4; ++r) {
        int c = c0 + cw * 64 + ci * 16 + quad * 4 + r;
        int n = n0 + nw * 32 + nj * 16 + la;
        size_t pko = ((size_t)(c >> 4) * 128 + (n >> 5)) * 512 + (c & 15) * 32 + (n & 31);
        out[((size_t)b * C_ + c) * N_ + n] = fmaf(gc, acc[ci][nj][r], bf2f(sb[pko]));
      }
}

// ---------------------------------------------------------------------------
extern "C" void kernel_launch(void* const* d_in, const int* in_sizes, int n_in,
                              void* d_out, int out_size, void* d_ws, size_t ws_size,
                              hipStream_t stream) {
  const float* x  = (const float*)d_in[0];
  const float* wq = (const float*)d_in[1];
  const float* bq = (const float*)d_in[2];
  const float* wk = (const float*)d_in[3];
  const float* bk = (const float*)d_in[4];
  const float* wv = (const float*)d_in[5];
  const float* bv = (const float*)d_in[6];
  const float* gp = (const float*)d_in[7];
  const float* gc = (const float*)d_in[8];
  float* out = (float*)d_out;

  char* ws = (char*)d_ws;
  // Region map (max used = 84.9 MB):
  //  A 0        : x_pk (16.78M)   -> later at_pk (2.1M)
  //  B 16.78M   : w_pk (1.05M)
  //  C 17.83M   : q_pk (8.39M)    (live through k_pam)
  //  D 26.21M   : k_pk (8.39M)    (live through k_pam)
  //  E 34.60M   : v_pk (16.78M)   -> later ep (16.78M)
  //  F 51.38M   : sa_pk (16.78M)
  //  G 68.16M   : saT_pk (16.78M)
  unsigned short* x_pk   = (unsigned short*)(ws);
  unsigned short* w_pk   = (unsigned short*)(ws + 16777216);
  unsigned short* q_pk   = (unsigned short*)(ws + 17825792);
  unsigned short* k_pk   = (unsigned short*)(ws + 26214400);
  unsigned short* v_pk   = (unsigned short*)(ws + 34603008);
  unsigned short* sa_pk  = (unsigned short*)(ws + 51380224);
  unsigned short* saT_pk = (unsigned short*)(ws + 68157440);
  float*          ep     = (float*)(ws + 34603008);            // reuse E
  unsigned short* at_pk  = (unsigned short*)(ws);              // reuse A

  k_prep<<<2304, 256, 0, stream>>>(x, wq, wk, wv, x_pk, w_pk);
  k_qkv<<<dim3(32, 8, B_), 512, 0, stream>>>(w_pk, x_pk, bq, bk, bv, q_pk, k_pk, v_pk);
  k_pam<<<256, 1024, 0, stream>>>(q_pk, k_pk, v_pk, x, gp, sa_pk, saT_pk);
  k_cam_e<<<dim3(36, 4, B_), 256, 0, stream>>>(sa_pk, ep);
  k_cam_softmax<<<dim3(C_, B_), 64, 0, stream>>>(ep, at_pk);
  k_cam_out<<<dim3(32, 4, B_), 512, 0, stream>>>(at_pk, saT_pk, sa_pk, gc, out);
}

// Round 17
// 340.721 us; speedup vs baseline: 1.0947x; 1.0483x over previous
//
#include <hip/hip_runtime.h>

#define B_ 4
#define C_ 512
#define CI_ 256
#define N_ 4096
#define SCALE_PAM 0.04419417382415922f  // 1/sqrt(512)
#define SCALE_CAM (1.0f/64.0f)          // 1/sqrt(4096)
#define SHIFT_PAM 8.0f

typedef float v4f __attribute__((ext_vector_type(4)));
typedef short v8s __attribute__((ext_vector_type(8)));

__device__ __forceinline__ unsigned short f2bf(float f) {
  unsigned int u = __float_as_uint(f);
  u = (u + 0x7FFFu + ((u >> 16) & 1u)) >> 16;
  return (unsigned short)u;
}
__device__ __forceinline__ float bf2f(unsigned short s) {
  return __uint_as_float(((unsigned int)s) << 16);
}
__device__ __forceinline__ v8s ld8(const unsigned short* p) {
  v8s r; *(int4*)&r = *(const int4*)p; return r;
}
__device__ __forceinline__ v4f mfma16(v8s a, v8s b, v4f c) {
  return __builtin_amdgcn_mfma_f32_16x16x32_bf16(a, b, c, 0, 0, 0);
}
// PK layout: off(r,k) = ((r>>4)*(K>>5) + (k>>5))*512 + (r&15)*32 + (k&31)  [shorts]
// Wave frag load: base + lanelin, lanelin=(lane&15)*32+(lane>>4)*8 -> contiguous 1KB.

// ---------------------------------------------------------------------------
// K_prep: fused k_xT + k_wb (independent work, one launch).
//  blocks [0,2048): x fp32 [b][c][n] -> x_pk PK(4096,512) per batch.
//  blocks [2048,2304): wq/wk/wv fp32 -> w_pk PK(1024,512).
// Branch is block-uniform -> LDS barrier in the xT path is safe.
// ---------------------------------------------------------------------------
__global__ __launch_bounds__(256) void k_prep(const float* __restrict__ x,
                                              const float* __restrict__ wq,
                                              const float* __restrict__ wk,
                                              const float* __restrict__ wv,
                                              unsigned short* __restrict__ x_pk,
                                              unsigned short* __restrict__ w_pk) {
  const int t = threadIdx.x;
  if (blockIdx.x >= 2048) {  // ---- wb part ----
    int u = (blockIdx.x - 2048) * 256 + t;
    int blk = u >> 6, wi = (u & 63) * 8;
    int r = (blk >> 4) * 16 + (wi >> 5);
    int k = (blk & 15) * 32 + (wi & 31);
    const float* src = (r < 256) ? &wq[r * 512 + k]
                     : (r < 512) ? &wk[(r - 256) * 512 + k]
                                 : &wv[(r - 512) * 512 + k];
    float4 f0 = *(const float4*)src, f1 = *(const float4*)(src + 4);
    ushort4 o0 = { f2bf(f0.x), f2bf(f0.y), f2bf(f0.z), f2bf(f0.w) };
    ushort4 o1 = { f2bf(f1.x), f2bf(f1.y), f2bf(f1.z), f2bf(f1.w) };
    *(ushort4*)&w_pk[u * 8] = o0;
    *(ushort4*)&w_pk[u * 8 + 4] = o1;
    return;
  }
  // ---- xT part ----
  const int b = blockIdx.x >> 9, c0 = ((blockIdx.x >> 6) & 7) * 64, n0 = (blockIdx.x & 63) * 64;
  __shared__ unsigned short ts[64 * 72];  // [n][c]
  const int cl = t >> 2, nseg = (t & 3) * 16;
  const float* xr = x + ((size_t)b * C_ + c0 + cl) * N_ + n0 + nseg;
#pragma unroll
  for (int k = 0; k < 4; ++k) {
    float4 f = *(const float4*)(xr + k * 4);
    ts[(nseg + k * 4 + 0) * 72 + cl] = f2bf(f.x);
    ts[(nseg + k * 4 + 1) * 72 + cl] = f2bf(f.y);
    ts[(nseg + k * 4 + 2) * 72 + cl] = f2bf(f.z);
    ts[(nseg + k * 4 + 3) * 72 + cl] = f2bf(f.w);
  }
  __syncthreads();
  unsigned short* dst = x_pk + (size_t)b * N_ * C_;
#pragma unroll
  for (int u = t; u < 512; u += 256) {
    int blk = u >> 6, wi = (u & 63) * 8;
    int rl = (blk >> 1) * 16 + (wi >> 5);
    int kl = (blk & 1) * 32 + (wi & 31);
    int gr = n0 + rl, gk = c0 + kl;
    size_t go = ((size_t)(gr >> 4) * 16 + (gk >> 5)) * 512 + (gr & 15) * 32 + (gk & 31);
    *(int4*)&dst[go] = *(int4*)&ts[rl * 72 + kl];
  }
}

// ---------------------------------------------------------------------------
// K_qkv v20: 256o x 128n tile (was 128o) -> x_pk B-panel read 4x instead of
// 8x (134->67 MB of L2/HBM traffic). 512 thr = 8 waves = ow(4x64o) x
// nw(2x64n); per wave acc[4][4] (64 VGPR), 8 ld8 + 16 MFMA per K-step.
// o-tiles align with q/k/v boundaries: y=0 -> q[0,256), y=1 -> k[256,512),
// y=2,3 -> v halves. Epilogue branches stay block-uniform. LDS 69.6 KB.
// ---------------------------------------------------------------------------
__global__ __launch_bounds__(512) void k_qkv(
    const unsigned short* __restrict__ w_pk, const unsigned short* __restrict__ x_pk,
    const float* __restrict__ bq, const float* __restrict__ bk, const float* __restrict__ bv,
    unsigned short* __restrict__ q_pk, unsigned short* __restrict__ k_pk,
    unsigned short* __restrict__ v_pk) {
  const int b = blockIdx.z, o0 = blockIdx.y * 256, n0 = blockIdx.x * 128;
  const int t = threadIdx.x, wave = t >> 6, lane = t & 63;
  const int la = lane & 15, quad = lane >> 4;
  const int ow = wave & 3, nw = wave >> 2;  // 4 o-subtiles(64) x 2 n-subtiles(64)
  const int lanelin = la * 32 + quad * 8;
  const unsigned short* xpb = x_pk + (size_t)b * N_ * C_;
  __shared__ unsigned short tp[256 * 136];  // 69.6 KB; q/k path views as [128][264]

  v4f acc[4][4];
#pragma unroll
  for (int i = 0; i < 4; ++i)
#pragma unroll
    for (int j = 0; j < 4; ++j) acc[i][j] = (v4f){0.f, 0.f, 0.f, 0.f};

  const int ar16 = (o0 + ow * 64) >> 4;
  const int br16 = (n0 + nw * 64) >> 4;
#pragma unroll 2
  for (int s = 0; s < 16; ++s) {
    v8s bfr[4], afr[4];
#pragma unroll
    for (int j = 0; j < 4; ++j)
      bfr[j] = ld8(&xpb[((size_t)(br16 + j) * 16 + s) * 512 + lanelin]);
#pragma unroll
    for (int i = 0; i < 4; ++i)
      afr[i] = ld8(&w_pk[((size_t)(ar16 + i) * 16 + s) * 512 + lanelin]);
#pragma unroll
    for (int i = 0; i < 4; ++i)
#pragma unroll
      for (int j = 0; j < 4; ++j)
        acc[i][j] = mfma16(afr[i], bfr[j], acc[i][j]);
  }

  if (o0 >= 512) {  // ---- v half: stage [c][n], emit PK(512,4096) ----
    const float* bias = bv + (o0 - 512);
#pragma unroll
    for (int oi = 0; oi < 4; ++oi)
#pragma unroll
      for (int nj = 0; nj < 4; ++nj)
#pragma unroll
        for (int r = 0; r < 4; ++r) {
          int cl = ow * 64 + oi * 16 + quad * 4 + r;
          int nl = nw * 64 + nj * 16 + la;
          tp[cl * 136 + nl] = f2bf(acc[oi][nj][r] + bias[cl]);
        }
    __syncthreads();
    unsigned short* dst = v_pk + (size_t)b * C_ * N_;
#pragma unroll
    for (int u = t; u < 4096; u += 512) {
      int rl = u >> 4, kl = (u & 15) * 8;
      int gr = (o0 - 512) + rl, gk = n0 + kl;
      size_t go = ((size_t)(gr >> 4) * 128 + (gk >> 5)) * 512 + (gr & 15) * 32 + (gk & 31);
      *(int4*)&dst[go] = *(int4*)&tp[rl * 136 + kl];
    }
  } else {  // ---- q or k (o0 = 0 or 256): stage [n][o], emit PK(4096,256) ----
    const float* bias = (o0 == 0) ? bq : bk;
#pragma unroll
    for (int oi = 0; oi < 4; ++oi)
#pragma unroll
      for (int nj = 0; nj < 4; ++nj)
#pragma unroll
        for (int r = 0; r < 4; ++r) {
          int ol = ow * 64 + oi * 16 + quad * 4 + r;
          int nl = nw * 64 + nj * 16 + la;
          tp[nl * 264 + ol] = f2bf(acc[oi][nj][r] + bias[ol]);
        }
    __syncthreads();
    unsigned short* dst = ((o0 == 0) ? q_pk : k_pk) + (size_t)b * N_ * CI_;
#pragma unroll
    for (int u = t; u < 4096; u += 512) {
      int rl = u >> 5, kl = (u & 31) * 8;
      int gr = n0 + rl, gk = kl;
      size_t go = ((size_t)(gr >> 4) * 8 + (gk >> 5)) * 512 + (gr & 15) * 32 + (gk & 31);
      *(int4*)&dst[go] = *(int4*)&tp[rl * 264 + kl];
    }
  }
}

// ---------------------------------------------------------------------------
// K_pam v15 (verified best): v8 core loop, full j range, fused combine
// epilogue emitting sa_pk + saT_pk.
// ---------------------------------------------------------------------------
__device__ __forceinline__ void kstage(const unsigned short* g, unsigned short* l, int t) {
  __builtin_amdgcn_global_load_lds(
      (const __attribute__((address_space(1))) void*)(g + (size_t)t * 8),
      (__attribute__((address_space(3))) void*)(l + t * 8), 16, 0, 0);
  __builtin_amdgcn_global_load_lds(
      (const __attribute__((address_space(1))) void*)(g + 8192 + (size_t)t * 8),
      (__attribute__((address_space(3))) void*)(l + 8192 + t * 8), 16, 0, 0);
}

__global__ __launch_bounds__(1024) void k_pam(
    const unsigned short* __restrict__ q_pk, const unsigned short* __restrict__ k_pk,
    const unsigned short* __restrict__ v_pk, const float* __restrict__ x,
    const float* __restrict__ gamma_pam,
    unsigned short* __restrict__ sa_pk, unsigned short* __restrict__ saT_pk) {
  const int blk = blockIdx.x;
  const int b = blk & 3, i0 = (blk >> 2) * 64;
  const int t = threadIdx.x, wave = t >> 6, lane = t & 63;
  const int la = lane & 15, quad = lane >> 4;
  const int iw = wave & 3, jw = wave >> 2;
  const int cb = wave * 32;
  const int lanelin = la * 32 + quad * 8;

  __shared__ unsigned short kls[3][16384];  // 3 x 32KB K tiles; reused by epilogue
  __shared__ unsigned short pa[2][4096];    // 64x64 P, XOR-swizzled stride 64
  __shared__ float l_lds[64];
  if (t < 64) l_lds[t] = 0.f;

  const unsigned short* qpk = q_pk + (size_t)b * N_ * CI_;
  const unsigned short* kpk = k_pk + (size_t)b * N_ * CI_;
  const unsigned short* vpk = v_pk + (size_t)b * C_ * N_;

  v8s qf[8];
  {
    const unsigned short* qb = qpk + ((size_t)((i0 >> 4) + iw) * 8) * 512 + lanelin;
#pragma unroll
    for (int s = 0; s < 8; ++s) qf[s] = ld8(qb + s * 512);
  }

  v4f acc[2][4];  // [ct][it]
#pragma unroll
  for (int ct = 0; ct < 2; ++ct)
#pragma unroll
    for (int it = 0; it < 4; ++it) acc[ct][it] = (v4f){0.f, 0.f, 0.f, 0.f};
  float lsum[4] = {0.f, 0.f, 0.f, 0.f};

  // prologue: stage step0 -> kls[0], step1 -> kls[1]; drain step0 only.
  kstage(kpk, kls[0], t);
  kstage(kpk + (size_t)4 * 4096, kls[1], t);
  asm volatile("s_waitcnt vmcnt(2)" ::: "memory");  // DMA_0 done (in-order drain)
  __builtin_amdgcn_s_barrier();
  __builtin_amdgcn_sched_barrier(0);

  int pb = 0;
  for (int step = 0; step < 64; ++step) {
    const int j0 = step * 64;
    // phase 1: V frags (issued FIRST so PV waits vmcnt(2), not 0)
    v8s vf[2][2];
#pragma unroll
    for (int ct = 0; ct < 2; ++ct)
#pragma unroll
      for (int ks = 0; ks < 2; ++ks)
        vf[ct][ks] = ld8(&vpk[((size_t)((cb >> 4) + ct) * 128 + (j0 >> 5) + ks) * 512 + lanelin]);
    __builtin_amdgcn_sched_barrier(0);
    // phase 2: DMA K tile for step+2 into kls[(step+2)%3]
    int jn = j0 + 128; if (jn >= N_) jn = 0;  // tail clamp (data unused)
    kstage(kpk + (size_t)(jn >> 4) * 4096, kls[(step + 2) % 3], t);
    __builtin_amdgcn_sched_barrier(0);
    // phase 3: S = Q K^T from kls[step%3] (staged 2 steps ago; guaranteed by
    // previous step's vmcnt(6)+s_barrier)
    const unsigned short* kb = &kls[step % 3][jw * 4096 + lanelin];
    v4f sA = (v4f){0.f, 0.f, 0.f, 0.f}, sB = sA;
#pragma unroll
    for (int sh = 0; sh < 4; ++sh) {
      sA = mfma16(qf[sh], ld8(kb + sh * 512), sA);
      sB = mfma16(qf[sh + 4], ld8(kb + (sh + 4) * 512), sB);
    }
    // phase 4: P = exp(s*scale - shift), swizzled LDS write
#pragma unroll
    for (int r = 0; r < 4; ++r) {
      float p = __expf((sA[r] + sB[r]) * SCALE_PAM - SHIFT_PAM);
      lsum[r] += p;
      int row = iw * 16 + quad * 4 + r;
      pa[pb][((row << 6) + jw * 16 + la) ^ ((row & 7) << 3)] = f2bf(p);
    }
    // phase 5: fence. lgkmcnt(0): our P writes visible. vmcnt(6): drains the
    // 2 oldest vmem = DMA for step+1 (queue: DMA_{t+1}(2), V_t(4), DMA_{t+2}(2)).
    __builtin_amdgcn_sched_barrier(0);
    asm volatile("s_waitcnt lgkmcnt(0) vmcnt(6)" ::: "memory");
    __builtin_amdgcn_s_barrier();
    __builtin_amdgcn_sched_barrier(0);
    // phase 6: PV: acc[c][i] += V[c][j] * P[i][j]  (compiler waits vmcnt(2) for vf)
    __builtin_amdgcn_s_setprio(1);
#pragma unroll
    for (int it = 0; it < 4; ++it) {
      const int row = it * 16 + la;
      const int sw = (row & 7) << 3;
#pragma unroll
      for (int ks = 0; ks < 2; ++ks) {
        v8s pf; *(int4*)&pf = *(const int4*)&pa[pb][((row << 6) + ks * 32 + quad * 8) ^ sw];
#pragma unroll
        for (int ct = 0; ct < 2; ++ct)
          acc[ct][it] = mfma16(vf[ct][ks], pf, acc[ct][it]);
      }
    }
    __builtin_amdgcn_s_setprio(0);
    pb ^= 1;
  }

  // ---- fused k_combine epilogue ----
#pragma unroll
  for (int r = 0; r < 4; ++r) {
    float v = lsum[r];
    v += __shfl_xor(v, 1); v += __shfl_xor(v, 2);
    v += __shfl_xor(v, 4); v += __shfl_xor(v, 8);
    if (la == 0) atomicAdd(&l_lds[iw * 16 + quad * 4 + r], v);
  }
  __syncthreads();  // l complete; all waves past PV (kls free to reuse)

  const float gpv = gamma_pam[0];
  unsigned short* ts = &kls[0][0];  // stage 1: ts[c][72] (512*72 shorts = 73.7KB)
  unsigned short sv[2][4][4];
#pragma unroll
  for (int ct = 0; ct < 2; ++ct)
#pragma unroll
    for (int it = 0; it < 4; ++it) {
      const int nl = it * 16 + la;
      const float lv = l_lds[nl] * (float)N_;
#pragma unroll
      for (int r = 0; r < 4; ++r) {
        const int c = cb + ct * 16 + quad * 4 + r;
        const float xv = x[((size_t)b * C_ + c) * N_ + i0 + nl];
        const unsigned short h = f2bf(tanhf(fmaf(gpv, acc[ct][it][r] / lv, xv)));
        sv[ct][it][r] = h;
        ts[c * 72 + nl] = h;
      }
    }
  __syncthreads();
  {  // sa_pk: PK(512 c, 4096 n), row-block stride 128
    unsigned short* dst = sa_pk + (size_t)b * C_ * N_;
#pragma unroll
    for (int u = t; u < 4096; u += 1024) {
      int c = u >> 3, n8 = (u & 7) * 8;
      int gn = i0 + n8;
      size_t go = ((size_t)(c >> 4) * 128 + (gn >> 5)) * 512 + (c & 15) * 32 + (gn & 31);
      *(int4*)&dst[go] = *(const int4*)&ts[c * 72 + n8];
    }
  }
  __syncthreads();
  unsigned short* ts2 = &kls[0][0];  // stage 2: ts2[n][520] (64*520 = 66.6KB)
#pragma unroll
  for (int ct = 0; ct < 2; ++ct)
#pragma unroll
    for (int it = 0; it < 4; ++it)
#pragma unroll
      for (int r = 0; r < 4; ++r)
        ts2[(it * 16 + la) * 520 + (cb + ct * 16 + quad * 4 + r)] = sv[ct][it][r];
  __syncthreads();
  {  // saT_pk: PK(4096 n, 512 c), row-block stride 16
    unsigned short* dst = saT_pk + (size_t)b * N_ * C_;
#pragma unroll
    for (int u = t; u < 4096; u += 1024) {
      int nl = u >> 6, c8 = (u & 63) * 8;
      int gn = i0 + nl;
      size_t go = ((size_t)(gn >> 4) * 16 + (c8 >> 5)) * 512 + (gn & 15) * 32 + (c8 & 31);
      *(int4*)&dst[go] = *(const int4*)&ts2[nl * 520 + c8];
    }
  }
}

// ---------------------------------------------------------------------------
// K_cam_e v18: SYMMETRIC — compute upper-triangle tiles only (36 of 64);
// off-diag tiles mirror via LDS transpose. Bitwise-identical e_part.
// ---------------------------------------------------------------------------
__global__ __launch_bounds__(256) void k_cam_e(const unsigned short* __restrict__ sa_pk,
                                               float* __restrict__ e_part) {
  const int b = blockIdx.z, ks = blockIdx.y;
  int idx = blockIdx.x;  // 0..35 -> (ci,di), ci <= di
  int ci = 0;
  while (idx >= 8 - ci) { idx -= 8 - ci; ++ci; }
  const int di = ci + idx;
  const int c0 = ci * 64, d0 = di * 64;
  const int t = threadIdx.x, wave = t >> 6, lane = t & 63;
  const int la = lane & 15, quad = lane >> 4;
  const int cw = wave & 1, dw = wave >> 1;
  const int lanelin = la * 32 + quad * 8;
  const unsigned short* sb = sa_pk + (size_t)b * C_ * N_;
  __shared__ float tr[64 * 65];

  v4f acc[2][2];
#pragma unroll
  for (int i = 0; i < 2; ++i)
#pragma unroll
    for (int j = 0; j < 2; ++j) acc[i][j] = (v4f){0.f, 0.f, 0.f, 0.f};

  const int ar16 = (c0 + cw * 32) >> 4;
  const int br16 = (d0 + dw * 32) >> 4;
#pragma unroll 4
  for (int s = 0; s < 32; ++s) {
    const int k32 = ks * 32 + s;
    v8s a0 = ld8(&sb[((size_t)(ar16 + 0) * 128 + k32) * 512 + lanelin]);
    v8s a1 = ld8(&sb[((size_t)(ar16 + 1) * 128 + k32) * 512 + lanelin]);
    v8s b0 = ld8(&sb[((size_t)(br16 + 0) * 128 + k32) * 512 + lanelin]);
    v8s b1 = ld8(&sb[((size_t)(br16 + 1) * 128 + k32) * 512 + lanelin]);
    acc[0][0] = mfma16(a0, b0, acc[0][0]);
    acc[0][1] = mfma16(a0, b1, acc[0][1]);
    acc[1][0] = mfma16(a1, b0, acc[1][0]);
    acc[1][1] = mfma16(a1, b1, acc[1][1]);
  }
  float* ep = e_part + ((size_t)(ks * B_ + b)) * C_ * C_;
#pragma unroll
  for (int i = 0; i < 2; ++i)
#pragma unroll
    for (int j = 0; j < 2; ++j)
#pragma unroll
      for (int r = 0; r < 4; ++r) {
        int cl = cw * 32 + i * 16 + quad * 4 + r;
        int dl = dw * 32 + j * 16 + la;
        float v = acc[i][j][r] * SCALE_CAM;
        ep[(size_t)(c0 + cl) * C_ + d0 + dl] = v;
        tr[dl * 65 + cl] = v;
      }
  if (ci != di) {  // mirror tile (block-uniform branch)
    __syncthreads();
#pragma unroll
    for (int u = t; u < 4096; u += 256) {
      int dl = u >> 6, cl = u & 63;
      ep[(size_t)(d0 + dl) * C_ + c0 + cl] = tr[dl * 65 + cl];
    }
  }
}

// ---------------------------------------------------------------------------
// K_cam_softmax: min-trick softmax over 4 parts -> attn_pk PK(512,512).
// ---------------------------------------------------------------------------
__global__ __launch_bounds__(64) void k_cam_softmax(const float* __restrict__ e_part,
                                                    unsigned short* __restrict__ attn_pk) {
  const int c = blockIdx.x, b = blockIdx.y, lane = threadIdx.x;
  size_t roff = ((size_t)b * C_ + c) * C_;
  float vals[8];
#pragma unroll
  for (int r = 0; r < 8; ++r) {
    int d = lane + r * 64;
    float s = 0.f;
#pragma unroll
    for (int p = 0; p < 4; ++p) s += e_part[(size_t)(p * B_) * C_ * C_ + roff + d];
    vals[r] = s;
  }
  float mn = vals[0];
#pragma unroll
  for (int r = 1; r < 8; ++r) mn = fminf(mn, vals[r]);
#pragma unroll
  for (int m = 32; m >= 1; m >>= 1) mn = fminf(mn, __shfl_xor(mn, m));
  float sum = 0.f;
#pragma unroll
  for (int r = 0; r < 8; ++r) { vals[r] = __expf(mn - vals[r]); sum += vals[r]; }
#pragma unroll
  for (int m = 32; m >= 1; m >>= 1) sum += __shfl_xor(sum, m);
  float sc = (1.0f / (float)C_) / sum;
  unsigned short* ab = attn_pk + (size_t)b * C_ * C_;
#pragma unroll
  for (int r = 0; r < 8; ++r) {
    int d = lane + r * 64;
    size_t go = ((size_t)(c >> 4) * 16 + (d >> 5)) * 512 + (c & 15) * 32 + (d & 31);
    ab[go] = f2bf(vals[r] * sc);
  }
}

// ---------------------------------------------------------------------------
// K_cam_out: out = gc * (attn @ sa) + sa.  128c x 128n tile, 512 thr.
// ---------------------------------------------------------------------------
__global__ __launch_bounds__(512) void k_cam_out(
    const unsigned short* __restrict__ attn_pk, const unsigned short* __restrict__ saT_pk,
    const unsigned short* __restrict__ sa_pk, const float* __restrict__ gamma_cam,
    float* __restrict__ out) {
  const int b = blockIdx.z, c0 = blockIdx.y * 128, n0 = blockIdx.x * 128;
  const int t = threadIdx.x, wave = t >> 6, lane = t & 63;
  const int la = lane & 15, quad = lane >> 4;
  const int cw = wave & 1, nw = wave >> 1;
  const int lanelin = la * 32 + quad * 8;
  const unsigned short* ab = attn_pk + (size_t)b * C_ * C_;
  const unsigned short* sTb = saT_pk + (size_t)b * N_ * C_;
  const unsigned short* sb = sa_pk + (size_t)b * C_ * N_;

  v4f acc[4][2];
#pragma unroll
  for (int i = 0; i < 4; ++i)
#pragma unroll
    for (int j = 0; j < 2; ++j) acc[i][j] = (v4f){0.f, 0.f, 0.f, 0.f};

  const int ar16 = (c0 + cw * 64) >> 4;
  const int br16 = (n0 + nw * 32) >> 4;
#pragma unroll 4
  for (int s = 0; s < 16; ++s) {
    v8s b0 = ld8(&sTb[((size_t)(br16 + 0) * 16 + s) * 512 + lanelin]);
    v8s b1 = ld8(&sTb[((size_t)(br16 + 1) * 16 + s) * 512 + lanelin]);
#pragma unroll
    for (int ci = 0; ci < 4; ++ci) {
      v8s a = ld8(&ab[((size_t)(ar16 + ci) * 16 + s) * 512 + lanelin]);
      acc[ci][0] = mfma16(a, b0, acc[ci][0]);
      acc[ci][1] = mfma16(a, b1, acc[ci][1]);
    }
  }
  const float gc = gamma_cam[0];
#pragma unroll
  for (int ci = 0; ci < 4; ++ci)
#pragma unroll
    for (int nj = 0; nj < 2; ++nj)
#pragma unroll
      for (int r = 0; r < 4; ++r) {
        int c = c0 + cw * 64 + ci * 16 + quad * 4 + r;
        int n = n0 + nw * 32 + nj * 16 + la;
        size_t pko = ((size_t)(c >> 4) * 128 + (n >> 5)) * 512 + (c & 15) * 32 + (n & 31);
        out[((size_t)b * C_ + c) * N_ + n] = fmaf(gc, acc[ci][nj][r], bf2f(sb[pko]));
      }
}

// ---------------------------------------------------------------------------
extern "C" void kernel_launch(void* const* d_in, const int* in_sizes, int n_in,
                              void* d_out, int out_size, void* d_ws, size_t ws_size,
                              hipStream_t stream) {
  const float* x  = (const float*)d_in[0];
  const float* wq = (const float*)d_in[1];
  const float* bq = (const float*)d_in[2];
  const float* wk = (const float*)d_in[3];
  const float* bk = (const float*)d_in[4];
  const float* wv = (const float*)d_in[5];
  const float* bv = (const float*)d_in[6];
  const float* gp = (const float*)d_in[7];
  const float* gc = (const float*)d_in[8];
  float* out = (float*)d_out;

  char* ws = (char*)d_ws;
  // Region map (max used = 84.9 MB):
  //  A 0        : x_pk (16.78M)   -> later at_pk (2.1M)
  //  B 16.78M   : w_pk (1.05M)
  //  C 17.83M   : q_pk (8.39M)    (live through k_pam)
  //  D 26.21M   : k_pk (8.39M)    (live through k_pam)
  //  E 34.60M   : v_pk (16.78M)   -> later ep (16.78M)
  //  F 51.38M   : sa_pk (16.78M)
  //  G 68.16M   : saT_pk (16.78M)
  unsigned short* x_pk   = (unsigned short*)(ws);
  unsigned short* w_pk   = (unsigned short*)(ws + 16777216);
  unsigned short* q_pk   = (unsigned short*)(ws + 17825792);
  unsigned short* k_pk   = (unsigned short*)(ws + 26214400);
  unsigned short* v_pk   = (unsigned short*)(ws + 34603008);
  unsigned short* sa_pk  = (unsigned short*)(ws + 51380224);
  unsigned short* saT_pk = (unsigned short*)(ws + 68157440);
  float*          ep     = (float*)(ws + 34603008);            // reuse E
  unsigned short* at_pk  = (unsigned short*)(ws);              // reuse A

  k_prep<<<2304, 256, 0, stream>>>(x, wq, wk, wv, x_pk, w_pk);
  k_qkv<<<dim3(32, 4, B_), 512, 0, stream>>>(w_pk, x_pk, bq, bk, bv, q_pk, k_pk, v_pk);
  k_pam<<<256, 1024, 0, stream>>>(q_pk, k_pk, v_pk, x, gp, sa_pk, saT_pk);
  k_cam_e<<<dim3(36, 4, B_), 256, 0, stream>>>(sa_pk, ep);
  k_cam_softmax<<<dim3(C_, B_), 64, 0, stream>>>(ep, at_pk);
  k_cam_out<<<dim3(32, 4, B_), 512, 0, stream>>>(at_pk, saT_pk, sa_pk, gc, out);
}

// Round 18
// 335.172 us; speedup vs baseline: 1.1128x; 1.0166x over previous
//
#include <hip/hip_runtime.h>

#define B_ 4
#define C_ 512
#define CI_ 256
#define N_ 4096
#define SCALE_PAM 0.04419417382415922f  // 1/sqrt(512)
#define SCALE_CAM (1.0f/64.0f)          // 1/sqrt(4096)
#define SHIFT_PAM 8.0f

typedef float v4f __attribute__((ext_vector_type(4)));
typedef short v8s __attribute__((ext_vector_type(8)));

__device__ __forceinline__ unsigned short f2bf(float f) {
  unsigned int u = __float_as_uint(f);
  u = (u + 0x7FFFu + ((u >> 16) & 1u)) >> 16;
  return (unsigned short)u;
}
__device__ __forceinline__ float bf2f(unsigned short s) {
  return __uint_as_float(((unsigned int)s) << 16);
}
__device__ __forceinline__ v8s ld8(const unsigned short* p) {
  v8s r; *(int4*)&r = *(const int4*)p; return r;
}
__device__ __forceinline__ v4f mfma16(v8s a, v8s b, v4f c) {
  return __builtin_amdgcn_mfma_f32_16x16x32_bf16(a, b, c, 0, 0, 0);
}
// PK layout: off(r,k) = ((r>>4)*(K>>5) + (k>>5))*512 + (r&15)*32 + (k&31)  [shorts]
// Wave frag load: base + lanelin, lanelin=(lane&15)*32+(lane>>4)*8 -> contiguous 1KB.

// ---------------------------------------------------------------------------
// K_prep: fused k_xT + k_wb (independent work, one launch).
//  blocks [0,2048): x fp32 [b][c][n] -> x_pk PK(4096,512) per batch.
//  blocks [2048,2304): wq/wk/wv fp32 -> w_pk PK(1024,512).
// Branch is block-uniform -> LDS barrier in the xT path is safe.
// ---------------------------------------------------------------------------
__global__ __launch_bounds__(256) void k_prep(const float* __restrict__ x,
                                              const float* __restrict__ wq,
                                              const float* __restrict__ wk,
                                              const float* __restrict__ wv,
                                              unsigned short* __restrict__ x_pk,
                                              unsigned short* __restrict__ w_pk) {
  const int t = threadIdx.x;
  if (blockIdx.x >= 2048) {  // ---- wb part ----
    int u = (blockIdx.x - 2048) * 256 + t;
    int blk = u >> 6, wi = (u & 63) * 8;
    int r = (blk >> 4) * 16 + (wi >> 5);
    int k = (blk & 15) * 32 + (wi & 31);
    const float* src = (r < 256) ? &wq[r * 512 + k]
                     : (r < 512) ? &wk[(r - 256) * 512 + k]
                                 : &wv[(r - 512) * 512 + k];
    float4 f0 = *(const float4*)src, f1 = *(const float4*)(src + 4);
    ushort4 o0 = { f2bf(f0.x), f2bf(f0.y), f2bf(f0.z), f2bf(f0.w) };
    ushort4 o1 = { f2bf(f1.x), f2bf(f1.y), f2bf(f1.z), f2bf(f1.w) };
    *(ushort4*)&w_pk[u * 8] = o0;
    *(ushort4*)&w_pk[u * 8 + 4] = o1;
    return;
  }
  // ---- xT part ----
  const int b = blockIdx.x >> 9, c0 = ((blockIdx.x >> 6) & 7) * 64, n0 = (blockIdx.x & 63) * 64;
  __shared__ unsigned short ts[64 * 72];  // [n][c]
  const int cl = t >> 2, nseg = (t & 3) * 16;
  const float* xr = x + ((size_t)b * C_ + c0 + cl) * N_ + n0 + nseg;
#pragma unroll
  for (int k = 0; k < 4; ++k) {
    float4 f = *(const float4*)(xr + k * 4);
    ts[(nseg + k * 4 + 0) * 72 + cl] = f2bf(f.x);
    ts[(nseg + k * 4 + 1) * 72 + cl] = f2bf(f.y);
    ts[(nseg + k * 4 + 2) * 72 + cl] = f2bf(f.z);
    ts[(nseg + k * 4 + 3) * 72 + cl] = f2bf(f.w);
  }
  __syncthreads();
  unsigned short* dst = x_pk + (size_t)b * N_ * C_;
#pragma unroll
  for (int u = t; u < 512; u += 256) {
    int blk = u >> 6, wi = (u & 63) * 8;
    int rl = (blk >> 1) * 16 + (wi >> 5);
    int kl = (blk & 1) * 32 + (wi & 31);
    int gr = n0 + rl, gk = c0 + kl;
    size_t go = ((size_t)(gr >> 4) * 16 + (gk >> 5)) * 512 + (gr & 15) * 32 + (gk & 31);
    *(int4*)&dst[go] = *(int4*)&ts[rl * 72 + kl];
  }
}

// ---------------------------------------------------------------------------
// K_qkv v20 (verified): 256o x 128n tile -> x_pk B-panel read 4x not 8x.
// 512 thr = 8 waves = ow(4x64o) x nw(2x64n); acc[4][4].
// ---------------------------------------------------------------------------
__global__ __launch_bounds__(512) void k_qkv(
    const unsigned short* __restrict__ w_pk, const unsigned short* __restrict__ x_pk,
    const float* __restrict__ bq, const float* __restrict__ bk, const float* __restrict__ bv,
    unsigned short* __restrict__ q_pk, unsigned short* __restrict__ k_pk,
    unsigned short* __restrict__ v_pk) {
  const int b = blockIdx.z, o0 = blockIdx.y * 256, n0 = blockIdx.x * 128;
  const int t = threadIdx.x, wave = t >> 6, lane = t & 63;
  const int la = lane & 15, quad = lane >> 4;
  const int ow = wave & 3, nw = wave >> 2;  // 4 o-subtiles(64) x 2 n-subtiles(64)
  const int lanelin = la * 32 + quad * 8;
  const unsigned short* xpb = x_pk + (size_t)b * N_ * C_;
  __shared__ unsigned short tp[256 * 136];  // 69.6 KB; q/k path views as [128][264]

  v4f acc[4][4];
#pragma unroll
  for (int i = 0; i < 4; ++i)
#pragma unroll
    for (int j = 0; j < 4; ++j) acc[i][j] = (v4f){0.f, 0.f, 0.f, 0.f};

  const int ar16 = (o0 + ow * 64) >> 4;
  const int br16 = (n0 + nw * 64) >> 4;
#pragma unroll 2
  for (int s = 0; s < 16; ++s) {
    v8s bfr[4], afr[4];
#pragma unroll
    for (int j = 0; j < 4; ++j)
      bfr[j] = ld8(&xpb[((size_t)(br16 + j) * 16 + s) * 512 + lanelin]);
#pragma unroll
    for (int i = 0; i < 4; ++i)
      afr[i] = ld8(&w_pk[((size_t)(ar16 + i) * 16 + s) * 512 + lanelin]);
#pragma unroll
    for (int i = 0; i < 4; ++i)
#pragma unroll
      for (int j = 0; j < 4; ++j)
        acc[i][j] = mfma16(afr[i], bfr[j], acc[i][j]);
  }

  if (o0 >= 512) {  // ---- v half: stage [c][n], emit PK(512,4096) ----
    const float* bias = bv + (o0 - 512);
#pragma unroll
    for (int oi = 0; oi < 4; ++oi)
#pragma unroll
      for (int nj = 0; nj < 4; ++nj)
#pragma unroll
        for (int r = 0; r < 4; ++r) {
          int cl = ow * 64 + oi * 16 + quad * 4 + r;
          int nl = nw * 64 + nj * 16 + la;
          tp[cl * 136 + nl] = f2bf(acc[oi][nj][r] + bias[cl]);
        }
    __syncthreads();
    unsigned short* dst = v_pk + (size_t)b * C_ * N_;
#pragma unroll
    for (int u = t; u < 4096; u += 512) {
      int rl = u >> 4, kl = (u & 15) * 8;
      int gr = (o0 - 512) + rl, gk = n0 + kl;
      size_t go = ((size_t)(gr >> 4) * 128 + (gk >> 5)) * 512 + (gr & 15) * 32 + (gk & 31);
      *(int4*)&dst[go] = *(int4*)&tp[rl * 136 + kl];
    }
  } else {  // ---- q or k (o0 = 0 or 256): stage [n][o], emit PK(4096,256) ----
    const float* bias = (o0 == 0) ? bq : bk;
#pragma unroll
    for (int oi = 0; oi < 4; ++oi)
#pragma unroll
      for (int nj = 0; nj < 4; ++nj)
#pragma unroll
        for (int r = 0; r < 4; ++r) {
          int ol = ow * 64 + oi * 16 + quad * 4 + r;
          int nl = nw * 64 + nj * 16 + la;
          tp[nl * 264 + ol] = f2bf(acc[oi][nj][r] + bias[ol]);
        }
    __syncthreads();
    unsigned short* dst = ((o0 == 0) ? q_pk : k_pk) + (size_t)b * N_ * CI_;
#pragma unroll
    for (int u = t; u < 4096; u += 512) {
      int rl = u >> 5, kl = (u & 31) * 8;
      int gr = n0 + rl, gk = kl;
      size_t go = ((size_t)(gr >> 4) * 8 + (gk >> 5)) * 512 + (gr & 15) * 32 + (gk & 31);
      *(int4*)&dst[go] = *(int4*)&tp[rl * 264 + kl];
    }
  }
}

// ---------------------------------------------------------------------------
// K_pam v15 (verified best): v8 core loop, full j range, fused combine
// epilogue emitting sa_pk + saT_pk.
// ---------------------------------------------------------------------------
__device__ __forceinline__ void kstage(const unsigned short* g, unsigned short* l, int t) {
  __builtin_amdgcn_global_load_lds(
      (const __attribute__((address_space(1))) void*)(g + (size_t)t * 8),
      (__attribute__((address_space(3))) void*)(l + t * 8), 16, 0, 0);
  __builtin_amdgcn_global_load_lds(
      (const __attribute__((address_space(1))) void*)(g + 8192 + (size_t)t * 8),
      (__attribute__((address_space(3))) void*)(l + 8192 + t * 8), 16, 0, 0);
}

__global__ __launch_bounds__(1024) void k_pam(
    const unsigned short* __restrict__ q_pk, const unsigned short* __restrict__ k_pk,
    const unsigned short* __restrict__ v_pk, const float* __restrict__ x,
    const float* __restrict__ gamma_pam,
    unsigned short* __restrict__ sa_pk, unsigned short* __restrict__ saT_pk) {
  const int blk = blockIdx.x;
  const int b = blk & 3, i0 = (blk >> 2) * 64;
  const int t = threadIdx.x, wave = t >> 6, lane = t & 63;
  const int la = lane & 15, quad = lane >> 4;
  const int iw = wave & 3, jw = wave >> 2;
  const int cb = wave * 32;
  const int lanelin = la * 32 + quad * 8;

  __shared__ unsigned short kls[3][16384];  // 3 x 32KB K tiles; reused by epilogue
  __shared__ unsigned short pa[2][4096];    // 64x64 P, XOR-swizzled stride 64
  __shared__ float l_lds[64];
  if (t < 64) l_lds[t] = 0.f;

  const unsigned short* qpk = q_pk + (size_t)b * N_ * CI_;
  const unsigned short* kpk = k_pk + (size_t)b * N_ * CI_;
  const unsigned short* vpk = v_pk + (size_t)b * C_ * N_;

  v8s qf[8];
  {
    const unsigned short* qb = qpk + ((size_t)((i0 >> 4) + iw) * 8) * 512 + lanelin;
#pragma unroll
    for (int s = 0; s < 8; ++s) qf[s] = ld8(qb + s * 512);
  }

  v4f acc[2][4];  // [ct][it]
#pragma unroll
  for (int ct = 0; ct < 2; ++ct)
#pragma unroll
    for (int it = 0; it < 4; ++it) acc[ct][it] = (v4f){0.f, 0.f, 0.f, 0.f};
  float lsum[4] = {0.f, 0.f, 0.f, 0.f};

  // prologue: stage step0 -> kls[0], step1 -> kls[1]; drain step0 only.
  kstage(kpk, kls[0], t);
  kstage(kpk + (size_t)4 * 4096, kls[1], t);
  asm volatile("s_waitcnt vmcnt(2)" ::: "memory");  // DMA_0 done (in-order drain)
  __builtin_amdgcn_s_barrier();
  __builtin_amdgcn_sched_barrier(0);

  int pb = 0;
  for (int step = 0; step < 64; ++step) {
    const int j0 = step * 64;
    // phase 1: V frags (issued FIRST so PV waits vmcnt(2), not 0)
    v8s vf[2][2];
#pragma unroll
    for (int ct = 0; ct < 2; ++ct)
#pragma unroll
      for (int ks = 0; ks < 2; ++ks)
        vf[ct][ks] = ld8(&vpk[((size_t)((cb >> 4) + ct) * 128 + (j0 >> 5) + ks) * 512 + lanelin]);
    __builtin_amdgcn_sched_barrier(0);
    // phase 2: DMA K tile for step+2 into kls[(step+2)%3]
    int jn = j0 + 128; if (jn >= N_) jn = 0;  // tail clamp (data unused)
    kstage(kpk + (size_t)(jn >> 4) * 4096, kls[(step + 2) % 3], t);
    __builtin_amdgcn_sched_barrier(0);
    // phase 3: S = Q K^T from kls[step%3] (staged 2 steps ago; guaranteed by
    // previous step's vmcnt(6)+s_barrier)
    const unsigned short* kb = &kls[step % 3][jw * 4096 + lanelin];
    v4f sA = (v4f){0.f, 0.f, 0.f, 0.f}, sB = sA;
#pragma unroll
    for (int sh = 0; sh < 4; ++sh) {
      sA = mfma16(qf[sh], ld8(kb + sh * 512), sA);
      sB = mfma16(qf[sh + 4], ld8(kb + (sh + 4) * 512), sB);
    }
    // phase 4: P = exp(s*scale - shift), swizzled LDS write
#pragma unroll
    for (int r = 0; r < 4; ++r) {
      float p = __expf((sA[r] + sB[r]) * SCALE_PAM - SHIFT_PAM);
      lsum[r] += p;
      int row = iw * 16 + quad * 4 + r;
      pa[pb][((row << 6) + jw * 16 + la) ^ ((row & 7) << 3)] = f2bf(p);
    }
    // phase 5: fence. lgkmcnt(0): our P writes visible. vmcnt(6): drains the
    // 2 oldest vmem = DMA for step+1 (queue: DMA_{t+1}(2), V_t(4), DMA_{t+2}(2)).
    __builtin_amdgcn_sched_barrier(0);
    asm volatile("s_waitcnt lgkmcnt(0) vmcnt(6)" ::: "memory");
    __builtin_amdgcn_s_barrier();
    __builtin_amdgcn_sched_barrier(0);
    // phase 6: PV: acc[c][i] += V[c][j] * P[i][j]  (compiler waits vmcnt(2) for vf)
    __builtin_amdgcn_s_setprio(1);
#pragma unroll
    for (int it = 0; it < 4; ++it) {
      const int row = it * 16 + la;
      const int sw = (row & 7) << 3;
#pragma unroll
      for (int ks = 0; ks < 2; ++ks) {
        v8s pf; *(int4*)&pf = *(const int4*)&pa[pb][((row << 6) + ks * 32 + quad * 8) ^ sw];
#pragma unroll
        for (int ct = 0; ct < 2; ++ct)
          acc[ct][it] = mfma16(vf[ct][ks], pf, acc[ct][it]);
      }
    }
    __builtin_amdgcn_s_setprio(0);
    pb ^= 1;
  }

  // ---- fused k_combine epilogue ----
#pragma unroll
  for (int r = 0; r < 4; ++r) {
    float v = lsum[r];
    v += __shfl_xor(v, 1); v += __shfl_xor(v, 2);
    v += __shfl_xor(v, 4); v += __shfl_xor(v, 8);
    if (la == 0) atomicAdd(&l_lds[iw * 16 + quad * 4 + r], v);
  }
  __syncthreads();  // l complete; all waves past PV (kls free to reuse)

  const float gpv = gamma_pam[0];
  unsigned short* ts = &kls[0][0];  // stage 1: ts[c][72] (512*72 shorts = 73.7KB)
  unsigned short sv[2][4][4];
#pragma unroll
  for (int ct = 0; ct < 2; ++ct)
#pragma unroll
    for (int it = 0; it < 4; ++it) {
      const int nl = it * 16 + la;
      const float lv = l_lds[nl] * (float)N_;
#pragma unroll
      for (int r = 0; r < 4; ++r) {
        const int c = cb + ct * 16 + quad * 4 + r;
        const float xv = x[((size_t)b * C_ + c) * N_ + i0 + nl];
        const unsigned short h = f2bf(tanhf(fmaf(gpv, acc[ct][it][r] / lv, xv)));
        sv[ct][it][r] = h;
        ts[c * 72 + nl] = h;
      }
    }
  __syncthreads();
  {  // sa_pk: PK(512 c, 4096 n), row-block stride 128
    unsigned short* dst = sa_pk + (size_t)b * C_ * N_;
#pragma unroll
    for (int u = t; u < 4096; u += 1024) {
      int c = u >> 3, n8 = (u & 7) * 8;
      int gn = i0 + n8;
      size_t go = ((size_t)(c >> 4) * 128 + (gn >> 5)) * 512 + (c & 15) * 32 + (gn & 31);
      *(int4*)&dst[go] = *(const int4*)&ts[c * 72 + n8];
    }
  }
  __syncthreads();
  unsigned short* ts2 = &kls[0][0];  // stage 2: ts2[n][520] (64*520 = 66.6KB)
#pragma unroll
  for (int ct = 0; ct < 2; ++ct)
#pragma unroll
    for (int it = 0; it < 4; ++it)
#pragma unroll
      for (int r = 0; r < 4; ++r)
        ts2[(it * 16 + la) * 520 + (cb + ct * 16 + quad * 4 + r)] = sv[ct][it][r];
  __syncthreads();
  {  // saT_pk: PK(4096 n, 512 c), row-block stride 16
    unsigned short* dst = saT_pk + (size_t)b * N_ * C_;
#pragma unroll
    for (int u = t; u < 4096; u += 1024) {
      int nl = u >> 6, c8 = (u & 63) * 8;
      int gn = i0 + nl;
      size_t go = ((size_t)(gn >> 4) * 16 + (c8 >> 5)) * 512 + (gn & 15) * 32 + (c8 & 31);
      *(int4*)&dst[go] = *(const int4*)&ts2[nl * 520 + c8];
    }
  }
}

// ---------------------------------------------------------------------------
// K_cam_e v18: SYMMETRIC — compute upper-triangle tiles only (36 of 64);
// off-diag tiles mirror via LDS transpose. Bitwise-identical e_part.
// ---------------------------------------------------------------------------
__global__ __launch_bounds__(256) void k_cam_e(const unsigned short* __restrict__ sa_pk,
                                               float* __restrict__ e_part) {
  const int b = blockIdx.z, ks = blockIdx.y;
  int idx = blockIdx.x;  // 0..35 -> (ci,di), ci <= di
  int ci = 0;
  while (idx >= 8 - ci) { idx -= 8 - ci; ++ci; }
  const int di = ci + idx;
  const int c0 = ci * 64, d0 = di * 64;
  const int t = threadIdx.x, wave = t >> 6, lane = t & 63;
  const int la = lane & 15, quad = lane >> 4;
  const int cw = wave & 1, dw = wave >> 1;
  const int lanelin = la * 32 + quad * 8;
  const unsigned short* sb = sa_pk + (size_t)b * C_ * N_;
  __shared__ float tr[64 * 65];

  v4f acc[2][2];
#pragma unroll
  for (int i = 0; i < 2; ++i)
#pragma unroll
    for (int j = 0; j < 2; ++j) acc[i][j] = (v4f){0.f, 0.f, 0.f, 0.f};

  const int ar16 = (c0 + cw * 32) >> 4;
  const int br16 = (d0 + dw * 32) >> 4;
#pragma unroll 4
  for (int s = 0; s < 32; ++s) {
    const int k32 = ks * 32 + s;
    v8s a0 = ld8(&sb[((size_t)(ar16 + 0) * 128 + k32) * 512 + lanelin]);
    v8s a1 = ld8(&sb[((size_t)(ar16 + 1) * 128 + k32) * 512 + lanelin]);
    v8s b0 = ld8(&sb[((size_t)(br16 + 0) * 128 + k32) * 512 + lanelin]);
    v8s b1 = ld8(&sb[((size_t)(br16 + 1) * 128 + k32) * 512 + lanelin]);
    acc[0][0] = mfma16(a0, b0, acc[0][0]);
    acc[0][1] = mfma16(a0, b1, acc[0][1]);
    acc[1][0] = mfma16(a1, b0, acc[1][0]);
    acc[1][1] = mfma16(a1, b1, acc[1][1]);
  }
  float* ep = e_part + ((size_t)(ks * B_ + b)) * C_ * C_;
#pragma unroll
  for (int i = 0; i < 2; ++i)
#pragma unroll
    for (int j = 0; j < 2; ++j)
#pragma unroll
      for (int r = 0; r < 4; ++r) {
        int cl = cw * 32 + i * 16 + quad * 4 + r;
        int dl = dw * 32 + j * 16 + la;
        float v = acc[i][j][r] * SCALE_CAM;
        ep[(size_t)(c0 + cl) * C_ + d0 + dl] = v;
        tr[dl * 65 + cl] = v;
      }
  if (ci != di) {  // mirror tile (block-uniform branch)
    __syncthreads();
#pragma unroll
    for (int u = t; u < 4096; u += 256) {
      int dl = u >> 6, cl = u & 63;
      ep[(size_t)(d0 + dl) * C_ + c0 + cl] = tr[dl * 65 + cl];
    }
  }
}

// ---------------------------------------------------------------------------
// K_cam_softmax: min-trick softmax over 4 parts -> attn_pk PK(512,512).
// ---------------------------------------------------------------------------
__global__ __launch_bounds__(64) void k_cam_softmax(const float* __restrict__ e_part,
                                                    unsigned short* __restrict__ attn_pk) {
  const int c = blockIdx.x, b = blockIdx.y, lane = threadIdx.x;
  size_t roff = ((size_t)b * C_ + c) * C_;
  float vals[8];
#pragma unroll
  for (int r = 0; r < 8; ++r) {
    int d = lane + r * 64;
    float s = 0.f;
#pragma unroll
    for (int p = 0; p < 4; ++p) s += e_part[(size_t)(p * B_) * C_ * C_ + roff + d];
    vals[r] = s;
  }
  float mn = vals[0];
#pragma unroll
  for (int r = 1; r < 8; ++r) mn = fminf(mn, vals[r]);
#pragma unroll
  for (int m = 32; m >= 1; m >>= 1) mn = fminf(mn, __shfl_xor(mn, m));
  float sum = 0.f;
#pragma unroll
  for (int r = 0; r < 8; ++r) { vals[r] = __expf(mn - vals[r]); sum += vals[r]; }
#pragma unroll
  for (int m = 32; m >= 1; m >>= 1) sum += __shfl_xor(sum, m);
  float sc = (1.0f / (float)C_) / sum;
  unsigned short* ab = attn_pk + (size_t)b * C_ * C_;
#pragma unroll
  for (int r = 0; r < 8; ++r) {
    int d = lane + r * 64;
    size_t go = ((size_t)(c >> 4) * 16 + (d >> 5)) * 512 + (c & 15) * 32 + (d & 31);
    ab[go] = f2bf(vals[r] * sc);
  }
}

// ---------------------------------------------------------------------------
// K_cam_out v21: 256c x 128n tile (k_qkv-v20 pattern) -> saT/attn panels
// read 2x not 4x. 512 thr = 8 waves = cw(4x64c) x nw(2x64n); acc[4][4].
// Per-element accumulation order unchanged -> bitwise-identical out.
// ---------------------------------------------------------------------------
__global__ __launch_bounds__(512) void k_cam_out(
    const unsigned short* __restrict__ attn_pk, const unsigned short* __restrict__ saT_pk,
    const unsigned short* __restrict__ sa_pk, const float* __restrict__ gamma_cam,
    float* __restrict__ out) {
  const int b = blockIdx.z, c0 = blockIdx.y * 256, n0 = blockIdx.x * 128;
  const int t = threadIdx.x, wave = t >> 6, lane = t & 63;
  const int la = lane & 15, quad = lane >> 4;
  const int cw = wave & 3, nw = wave >> 2;  // 4 c-subtiles(64) x 2 n-subtiles(64)
  const int lanelin = la * 32 + quad * 8;
  const unsigned short* ab = attn_pk + (size_t)b * C_ * C_;
  const unsigned short* sTb = saT_pk + (size_t)b * N_ * C_;
  const unsigned short* sb = sa_pk + (size_t)b * C_ * N_;

  v4f acc[4][4];
#pragma unroll
  for (int i = 0; i < 4; ++i)
#pragma unroll
    for (int j = 0; j < 4; ++j) acc[i][j] = (v4f){0.f, 0.f, 0.f, 0.f};

  const int ar16 = (c0 + cw * 64) >> 4;
  const int br16 = (n0 + nw * 64) >> 4;
#pragma unroll 2
  for (int s = 0; s < 16; ++s) {
    v8s bfr[4], afr[4];
#pragma unroll
    for (int j = 0; j < 4; ++j)
      bfr[j] = ld8(&sTb[((size_t)(br16 + j) * 16 + s) * 512 + lanelin]);
#pragma unroll
    for (int i = 0; i < 4; ++i)
      afr[i] = ld8(&ab[((size_t)(ar16 + i) * 16 + s) * 512 + lanelin]);
#pragma unroll
    for (int i = 0; i < 4; ++i)
#pragma unroll
      for (int j = 0; j < 4; ++j)
        acc[i][j] = mfma16(afr[i], bfr[j], acc[i][j]);
  }
  const float gc = gamma_cam[0];
#pragma unroll
  for (int ci = 0; ci < 4; ++ci)
#pragma unroll
    for (int nj = 0; nj < 4; ++nj)
#pragma unroll
      for (int r = 0; r < 4; ++r) {
        int c = c0 + cw * 64 + ci * 16 + quad * 4 + r;
        int n = n0 + nw * 64 + nj * 16 + la;
        size_t pko = ((size_t)(c >> 4) * 128 + (n >> 5)) * 512 + (c & 15) * 32 + (n & 31);
        out[((size_t)b * C_ + c) * N_ + n] = fmaf(gc, acc[ci][nj][r], bf2f(sb[pko]));
      }
}

// ---------------------------------------------------------------------------
extern "C" void kernel_launch(void* const* d_in, const int* in_sizes, int n_in,
                              void* d_out, int out_size, void* d_ws, size_t ws_size,
                              hipStream_t stream) {
  const float* x  = (const float*)d_in[0];
  const float* wq = (const float*)d_in[1];
  const float* bq = (const float*)d_in[2];
  const float* wk = (const float*)d_in[3];
  const float* bk = (const float*)d_in[4];
  const float* wv = (const float*)d_in[5];
  const float* bv = (const float*)d_in[6];
  const float* gp = (const float*)d_in[7];
  const float* gc = (const float*)d_in[8];
  float* out = (float*)d_out;

  char* ws = (char*)d_ws;
  // Region map (max used = 84.9 MB):
  //  A 0        : x_pk (16.78M)   -> later at_pk (2.1M)
  //  B 16.78M   : w_pk (1.05M)
  //  C 17.83M   : q_pk (8.39M)    (live through k_pam)
  //  D 26.21M   : k_pk (8.39M)    (live through k_pam)
  //  E 34.60M   : v_pk (16.78M)   -> later ep (16.78M)
  //  F 51.38M   : sa_pk (16.78M)
  //  G 68.16M   : saT_pk (16.78M)
  unsigned short* x_pk   = (unsigned short*)(ws);
  unsigned short* w_pk   = (unsigned short*)(ws + 16777216);
  unsigned short* q_pk   = (unsigned short*)(ws + 17825792);
  unsigned short* k_pk   = (unsigned short*)(ws + 26214400);
  unsigned short* v_pk   = (unsigned short*)(ws + 34603008);
  unsigned short* sa_pk  = (unsigned short*)(ws + 51380224);
  unsigned short* saT_pk = (unsigned short*)(ws + 68157440);
  float*          ep     = (float*)(ws + 34603008);            // reuse E
  unsigned short* at_pk  = (unsigned short*)(ws);              // reuse A

  k_prep<<<2304, 256, 0, stream>>>(x, wq, wk, wv, x_pk, w_pk);
  k_qkv<<<dim3(32, 4, B_), 512, 0, stream>>>(w_pk, x_pk, bq, bk, bv, q_pk, k_pk, v_pk);
  k_pam<<<256, 1024, 0, stream>>>(q_pk, k_pk, v_pk, x, gp, sa_pk, saT_pk);
  k_cam_e<<<dim3(36, 4, B_), 256, 0, stream>>>(sa_pk, ep);
  k_cam_softmax<<<dim3(C_, B_), 64, 0, stream>>>(ep, at_pk);
  k_cam_out<<<dim3(32, 2, B_), 512, 0, stream>>>(at_pk, saT_pk, sa_pk, gc, out);
}

// Round 19
// 331.504 us; speedup vs baseline: 1.1251x; 1.0111x over previous
//
#include <hip/hip_runtime.h>

#define B_ 4
#define C_ 512
#define CI_ 256
#define N_ 4096
#define SCALE_PAM 0.04419417382415922f  // 1/sqrt(512)
#define SCALE_CAM (1.0f/64.0f)          // 1/sqrt(4096)
#define SHIFT_PAM 8.0f

typedef float v4f __attribute__((ext_vector_type(4)));
typedef short v8s __attribute__((ext_vector_type(8)));

__device__ __forceinline__ unsigned short f2bf(float f) {
  unsigned int u = __float_as_uint(f);
  u = (u + 0x7FFFu + ((u >> 16) & 1u)) >> 16;
  return (unsigned short)u;
}
__device__ __forceinline__ float bf2f(unsigned short s) {
  return __uint_as_float(((unsigned int)s) << 16);
}
__device__ __forceinline__ v8s ld8(const unsigned short* p) {
  v8s r; *(int4*)&r = *(const int4*)p; return r;
}
__device__ __forceinline__ v4f mfma16(v8s a, v8s b, v4f c) {
  return __builtin_amdgcn_mfma_f32_16x16x32_bf16(a, b, c, 0, 0, 0);
}
// PK layout: off(r,k) = ((r>>4)*(K>>5) + (k>>5))*512 + (r&15)*32 + (k&31)  [shorts]
// Wave frag load: base + lanelin, lanelin=(lane&15)*32+(lane>>4)*8 -> contiguous 1KB.

// ---------------------------------------------------------------------------
// K_prep: fused k_xT + k_wb (independent work, one launch).
//  blocks [0,2048): x fp32 [b][c][n] -> x_pk PK(4096,512) per batch.
//  blocks [2048,2304): wq/wk/wv fp32 -> w_pk PK(1024,512).
// Branch is block-uniform -> LDS barrier in the xT path is safe.
// ---------------------------------------------------------------------------
__global__ __launch_bounds__(256) void k_prep(const float* __restrict__ x,
                                              const float* __restrict__ wq,
                                              const float* __restrict__ wk,
                                              const float* __restrict__ wv,
                                              unsigned short* __restrict__ x_pk,
                                              unsigned short* __restrict__ w_pk) {
  const int t = threadIdx.x;
  if (blockIdx.x >= 2048) {  // ---- wb part ----
    int u = (blockIdx.x - 2048) * 256 + t;
    int blk = u >> 6, wi = (u & 63) * 8;
    int r = (blk >> 4) * 16 + (wi >> 5);
    int k = (blk & 15) * 32 + (wi & 31);
    const float* src = (r < 256) ? &wq[r * 512 + k]
                     : (r < 512) ? &wk[(r - 256) * 512 + k]
                                 : &wv[(r - 512) * 512 + k];
    float4 f0 = *(const float4*)src, f1 = *(const float4*)(src + 4);
    ushort4 o0 = { f2bf(f0.x), f2bf(f0.y), f2bf(f0.z), f2bf(f0.w) };
    ushort4 o1 = { f2bf(f1.x), f2bf(f1.y), f2bf(f1.z), f2bf(f1.w) };
    *(ushort4*)&w_pk[u * 8] = o0;
    *(ushort4*)&w_pk[u * 8 + 4] = o1;
    return;
  }
  // ---- xT part ----
  const int b = blockIdx.x >> 9, c0 = ((blockIdx.x >> 6) & 7) * 64, n0 = (blockIdx.x & 63) * 64;
  __shared__ unsigned short ts[64 * 72];  // [n][c]
  const int cl = t >> 2, nseg = (t & 3) * 16;
  const float* xr = x + ((size_t)b * C_ + c0 + cl) * N_ + n0 + nseg;
#pragma unroll
  for (int k = 0; k < 4; ++k) {
    float4 f = *(const float4*)(xr + k * 4);
    ts[(nseg + k * 4 + 0) * 72 + cl] = f2bf(f.x);
    ts[(nseg + k * 4 + 1) * 72 + cl] = f2bf(f.y);
    ts[(nseg + k * 4 + 2) * 72 + cl] = f2bf(f.z);
    ts[(nseg + k * 4 + 3) * 72 + cl] = f2bf(f.w);
  }
  __syncthreads();
  unsigned short* dst = x_pk + (size_t)b * N_ * C_;
#pragma unroll
  for (int u = t; u < 512; u += 256) {
    int blk = u >> 6, wi = (u & 63) * 8;
    int rl = (blk >> 1) * 16 + (wi >> 5);
    int kl = (blk & 1) * 32 + (wi & 31);
    int gr = n0 + rl, gk = c0 + kl;
    size_t go = ((size_t)(gr >> 4) * 16 + (gk >> 5)) * 512 + (gr & 15) * 32 + (gk & 31);
    *(int4*)&dst[go] = *(int4*)&ts[rl * 72 + kl];
  }
}

// ---------------------------------------------------------------------------
// K_qkv v22: 256o x 256n tile (n widened from 128) -> x_pk B-panel read 2x
// not 4x (67->34 MB). Grid (16,4,B) = 256 blocks = exactly 1/CU, no tail.
// 512 thr = 8 waves = ow(4x64o) x nw(2x128n); acc[4][8] (128 VGPR) + ~60
// transient < 256 budget at 2 waves/SIMD. Epilogue LDS 256x264 = 135 KB.
// Per-output k-chain order unchanged -> bitwise-identical q/k/v.
// ---------------------------------------------------------------------------
__global__ __launch_bounds__(512) void k_qkv(
    const unsigned short* __restrict__ w_pk, const unsigned short* __restrict__ x_pk,
    const float* __restrict__ bq, const float* __restrict__ bk, const float* __restrict__ bv,
    unsigned short* __restrict__ q_pk, unsigned short* __restrict__ k_pk,
    unsigned short* __restrict__ v_pk) {
  const int b = blockIdx.z, o0 = blockIdx.y * 256, n0 = blockIdx.x * 256;
  const int t = threadIdx.x, wave = t >> 6, lane = t & 63;
  const int la = lane & 15, quad = lane >> 4;
  const int ow = wave & 3, nw = wave >> 2;  // 4 o-subtiles(64) x 2 n-subtiles(128)
  const int lanelin = la * 32 + quad * 8;
  const unsigned short* xpb = x_pk + (size_t)b * N_ * C_;
  __shared__ unsigned short tp[256 * 264];  // 135 KB; both paths use stride 264

  v4f acc[4][8];
#pragma unroll
  for (int i = 0; i < 4; ++i)
#pragma unroll
    for (int j = 0; j < 8; ++j) acc[i][j] = (v4f){0.f, 0.f, 0.f, 0.f};

  const int ar16 = (o0 + ow * 64) >> 4;
  const int br16 = (n0 + nw * 128) >> 4;
  for (int s = 0; s < 16; ++s) {
    v8s bfr[8], afr[4];
#pragma unroll
    for (int j = 0; j < 8; ++j)
      bfr[j] = ld8(&xpb[((size_t)(br16 + j) * 16 + s) * 512 + lanelin]);
#pragma unroll
    for (int i = 0; i < 4; ++i)
      afr[i] = ld8(&w_pk[((size_t)(ar16 + i) * 16 + s) * 512 + lanelin]);
#pragma unroll
    for (int i = 0; i < 4; ++i)
#pragma unroll
      for (int j = 0; j < 8; ++j)
        acc[i][j] = mfma16(afr[i], bfr[j], acc[i][j]);
  }

  if (o0 >= 512) {  // ---- v half: stage [c][n], emit PK(512,4096) ----
    const float* bias = bv + (o0 - 512);
#pragma unroll
    for (int oi = 0; oi < 4; ++oi)
#pragma unroll
      for (int nj = 0; nj < 8; ++nj)
#pragma unroll
        for (int r = 0; r < 4; ++r) {
          int cl = ow * 64 + oi * 16 + quad * 4 + r;
          int nl = nw * 128 + nj * 16 + la;
          tp[cl * 264 + nl] = f2bf(acc[oi][nj][r] + bias[cl]);
        }
    __syncthreads();
    unsigned short* dst = v_pk + (size_t)b * C_ * N_;
#pragma unroll
    for (int u = t; u < 8192; u += 512) {
      int rl = u >> 5, kl = (u & 31) * 8;
      int gr = (o0 - 512) + rl, gk = n0 + kl;
      size_t go = ((size_t)(gr >> 4) * 128 + (gk >> 5)) * 512 + (gr & 15) * 32 + (gk & 31);
      *(int4*)&dst[go] = *(int4*)&tp[rl * 264 + kl];
    }
  } else {  // ---- q or k (o0 = 0 or 256): stage [n][o], emit PK(4096,256) ----
    const float* bias = (o0 == 0) ? bq : bk;
#pragma unroll
    for (int oi = 0; oi < 4; ++oi)
#pragma unroll
      for (int nj = 0; nj < 8; ++nj)
#pragma unroll
        for (int r = 0; r < 4; ++r) {
          int ol = ow * 64 + oi * 16 + quad * 4 + r;
          int nl = nw * 128 + nj * 16 + la;
          tp[nl * 264 + ol] = f2bf(acc[oi][nj][r] + bias[ol]);
        }
    __syncthreads();
    unsigned short* dst = ((o0 == 0) ? q_pk : k_pk) + (size_t)b * N_ * CI_;
#pragma unroll
    for (int u = t; u < 8192; u += 512) {
      int rl = u >> 5, kl = (u & 31) * 8;
      int gr = n0 + rl, gk = kl;
      size_t go = ((size_t)(gr >> 4) * 8 + (gk >> 5)) * 512 + (gr & 15) * 32 + (gk & 31);
      *(int4*)&dst[go] = *(int4*)&tp[rl * 264 + kl];
    }
  }
}

// ---------------------------------------------------------------------------
// K_pam v15 (verified best): v8 core loop, full j range, fused combine
// epilogue emitting sa_pk + saT_pk.
// ---------------------------------------------------------------------------
__device__ __forceinline__ void kstage(const unsigned short* g, unsigned short* l, int t) {
  __builtin_amdgcn_global_load_lds(
      (const __attribute__((address_space(1))) void*)(g + (size_t)t * 8),
      (__attribute__((address_space(3))) void*)(l + t * 8), 16, 0, 0);
  __builtin_amdgcn_global_load_lds(
      (const __attribute__((address_space(1))) void*)(g + 8192 + (size_t)t * 8),
      (__attribute__((address_space(3))) void*)(l + 8192 + t * 8), 16, 0, 0);
}

__global__ __launch_bounds__(1024) void k_pam(
    const unsigned short* __restrict__ q_pk, const unsigned short* __restrict__ k_pk,
    const unsigned short* __restrict__ v_pk, const float* __restrict__ x,
    const float* __restrict__ gamma_pam,
    unsigned short* __restrict__ sa_pk, unsigned short* __restrict__ saT_pk) {
  const int blk = blockIdx.x;
  const int b = blk & 3, i0 = (blk >> 2) * 64;
  const int t = threadIdx.x, wave = t >> 6, lane = t & 63;
  const int la = lane & 15, quad = lane >> 4;
  const int iw = wave & 3, jw = wave >> 2;
  const int cb = wave * 32;
  const int lanelin = la * 32 + quad * 8;

  __shared__ unsigned short kls[3][16384];  // 3 x 32KB K tiles; reused by epilogue
  __shared__ unsigned short pa[2][4096];    // 64x64 P, XOR-swizzled stride 64
  __shared__ float l_lds[64];
  if (t < 64) l_lds[t] = 0.f;

  const unsigned short* qpk = q_pk + (size_t)b * N_ * CI_;
  const unsigned short* kpk = k_pk + (size_t)b * N_ * CI_;
  const unsigned short* vpk = v_pk + (size_t)b * C_ * N_;

  v8s qf[8];
  {
    const unsigned short* qb = qpk + ((size_t)((i0 >> 4) + iw) * 8) * 512 + lanelin;
#pragma unroll
    for (int s = 0; s < 8; ++s) qf[s] = ld8(qb + s * 512);
  }

  v4f acc[2][4];  // [ct][it]
#pragma unroll
  for (int ct = 0; ct < 2; ++ct)
#pragma unroll
    for (int it = 0; it < 4; ++it) acc[ct][it] = (v4f){0.f, 0.f, 0.f, 0.f};
  float lsum[4] = {0.f, 0.f, 0.f, 0.f};

  // prologue: stage step0 -> kls[0], step1 -> kls[1]; drain step0 only.
  kstage(kpk, kls[0], t);
  kstage(kpk + (size_t)4 * 4096, kls[1], t);
  asm volatile("s_waitcnt vmcnt(2)" ::: "memory");  // DMA_0 done (in-order drain)
  __builtin_amdgcn_s_barrier();
  __builtin_amdgcn_sched_barrier(0);

  int pb = 0;
  for (int step = 0; step < 64; ++step) {
    const int j0 = step * 64;
    // phase 1: V frags (issued FIRST so PV waits vmcnt(2), not 0)
    v8s vf[2][2];
#pragma unroll
    for (int ct = 0; ct < 2; ++ct)
#pragma unroll
      for (int ks = 0; ks < 2; ++ks)
        vf[ct][ks] = ld8(&vpk[((size_t)((cb >> 4) + ct) * 128 + (j0 >> 5) + ks) * 512 + lanelin]);
    __builtin_amdgcn_sched_barrier(0);
    // phase 2: DMA K tile for step+2 into kls[(step+2)%3]
    int jn = j0 + 128; if (jn >= N_) jn = 0;  // tail clamp (data unused)
    kstage(kpk + (size_t)(jn >> 4) * 4096, kls[(step + 2) % 3], t);
    __builtin_amdgcn_sched_barrier(0);
    // phase 3: S = Q K^T from kls[step%3] (staged 2 steps ago; guaranteed by
    // previous step's vmcnt(6)+s_barrier)
    const unsigned short* kb = &kls[step % 3][jw * 4096 + lanelin];
    v4f sA = (v4f){0.f, 0.f, 0.f, 0.f}, sB = sA;
#pragma unroll
    for (int sh = 0; sh < 4; ++sh) {
      sA = mfma16(qf[sh], ld8(kb + sh * 512), sA);
      sB = mfma16(qf[sh + 4], ld8(kb + (sh + 4) * 512), sB);
    }
    // phase 4: P = exp(s*scale - shift), swizzled LDS write
#pragma unroll
    for (int r = 0; r < 4; ++r) {
      float p = __expf((sA[r] + sB[r]) * SCALE_PAM - SHIFT_PAM);
      lsum[r] += p;
      int row = iw * 16 + quad * 4 + r;
      pa[pb][((row << 6) + jw * 16 + la) ^ ((row & 7) << 3)] = f2bf(p);
    }
    // phase 5: fence. lgkmcnt(0): our P writes visible. vmcnt(6): drains the
    // 2 oldest vmem = DMA for step+1 (queue: DMA_{t+1}(2), V_t(4), DMA_{t+2}(2)).
    __builtin_amdgcn_sched_barrier(0);
    asm volatile("s_waitcnt lgkmcnt(0) vmcnt(6)" ::: "memory");
    __builtin_amdgcn_s_barrier();
    __builtin_amdgcn_sched_barrier(0);
    // phase 6: PV: acc[c][i] += V[c][j] * P[i][j]  (compiler waits vmcnt(2) for vf)
    __builtin_amdgcn_s_setprio(1);
#pragma unroll
    for (int it = 0; it < 4; ++it) {
      const int row = it * 16 + la;
      const int sw = (row & 7) << 3;
#pragma unroll
      for (int ks = 0; ks < 2; ++ks) {
        v8s pf; *(int4*)&pf = *(const int4*)&pa[pb][((row << 6) + ks * 32 + quad * 8) ^ sw];
#pragma unroll
        for (int ct = 0; ct < 2; ++ct)
          acc[ct][it] = mfma16(vf[ct][ks], pf, acc[ct][it]);
      }
    }
    __builtin_amdgcn_s_setprio(0);
    pb ^= 1;
  }

  // ---- fused k_combine epilogue ----
#pragma unroll
  for (int r = 0; r < 4; ++r) {
    float v = lsum[r];
    v += __shfl_xor(v, 1); v += __shfl_xor(v, 2);
    v += __shfl_xor(v, 4); v += __shfl_xor(v, 8);
    if (la == 0) atomicAdd(&l_lds[iw * 16 + quad * 4 + r], v);
  }
  __syncthreads();  // l complete; all waves past PV (kls free to reuse)

  const float gpv = gamma_pam[0];
  unsigned short* ts = &kls[0][0];  // stage 1: ts[c][72] (512*72 shorts = 73.7KB)
  unsigned short sv[2][4][4];
#pragma unroll
  for (int ct = 0; ct < 2; ++ct)
#pragma unroll
    for (int it = 0; it < 4; ++it) {
      const int nl = it * 16 + la;
      const float lv = l_lds[nl] * (float)N_;
#pragma unroll
      for (int r = 0; r < 4; ++r) {
        const int c = cb + ct * 16 + quad * 4 + r;
        const float xv = x[((size_t)b * C_ + c) * N_ + i0 + nl];
        const unsigned short h = f2bf(tanhf(fmaf(gpv, acc[ct][it][r] / lv, xv)));
        sv[ct][it][r] = h;
        ts[c * 72 + nl] = h;
      }
    }
  __syncthreads();
  {  // sa_pk: PK(512 c, 4096 n), row-block stride 128
    unsigned short* dst = sa_pk + (size_t)b * C_ * N_;
#pragma unroll
    for (int u = t; u < 4096; u += 1024) {
      int c = u >> 3, n8 = (u & 7) * 8;
      int gn = i0 + n8;
      size_t go = ((size_t)(c >> 4) * 128 + (gn >> 5)) * 512 + (c & 15) * 32 + (gn & 31);
      *(int4*)&dst[go] = *(const int4*)&ts[c * 72 + n8];
    }
  }
  __syncthreads();
  unsigned short* ts2 = &kls[0][0];  // stage 2: ts2[n][520] (64*520 = 66.6KB)
#pragma unroll
  for (int ct = 0; ct < 2; ++ct)
#pragma unroll
    for (int it = 0; it < 4; ++it)
#pragma unroll
      for (int r = 0; r < 4; ++r)
        ts2[(it * 16 + la) * 520 + (cb + ct * 16 + quad * 4 + r)] = sv[ct][it][r];
  __syncthreads();
  {  // saT_pk: PK(4096 n, 512 c), row-block stride 16
    unsigned short* dst = saT_pk + (size_t)b * N_ * C_;
#pragma unroll
    for (int u = t; u < 4096; u += 1024) {
      int nl = u >> 6, c8 = (u & 63) * 8;
      int gn = i0 + nl;
      size_t go = ((size_t)(gn >> 4) * 16 + (c8 >> 5)) * 512 + (gn & 15) * 32 + (c8 & 31);
      *(int4*)&dst[go] = *(const int4*)&ts2[nl * 520 + c8];
    }
  }
}

// ---------------------------------------------------------------------------
// K_cam_e v18: SYMMETRIC — compute upper-triangle tiles only (36 of 64);
// off-diag tiles mirror via LDS transpose. Bitwise-identical e_part.
// ---------------------------------------------------------------------------
__global__ __launch_bounds__(256) void k_cam_e(const unsigned short* __restrict__ sa_pk,
                                               float* __restrict__ e_part) {
  const int b = blockIdx.z, ks = blockIdx.y;
  int idx = blockIdx.x;  // 0..35 -> (ci,di), ci <= di
  int ci = 0;
  while (idx >= 8 - ci) { idx -= 8 - ci; ++ci; }
  const int di = ci + idx;
  const int c0 = ci * 64, d0 = di * 64;
  const int t = threadIdx.x, wave = t >> 6, lane = t & 63;
  const int la = lane & 15, quad = lane >> 4;
  const int cw = wave & 1, dw = wave >> 1;
  const int lanelin = la * 32 + quad * 8;
  const unsigned short* sb = sa_pk + (size_t)b * C_ * N_;
  __shared__ float tr[64 * 65];

  v4f acc[2][2];
#pragma unroll
  for (int i = 0; i < 2; ++i)
#pragma unroll
    for (int j = 0; j < 2; ++j) acc[i][j] = (v4f){0.f, 0.f, 0.f, 0.f};

  const int ar16 = (c0 + cw * 32) >> 4;
  const int br16 = (d0 + dw * 32) >> 4;
#pragma unroll 4
  for (int s = 0; s < 32; ++s) {
    const int k32 = ks * 32 + s;
    v8s a0 = ld8(&sb[((size_t)(ar16 + 0) * 128 + k32) * 512 + lanelin]);
    v8s a1 = ld8(&sb[((size_t)(ar16 + 1) * 128 + k32) * 512 + lanelin]);
    v8s b0 = ld8(&sb[((size_t)(br16 + 0) * 128 + k32) * 512 + lanelin]);
    v8s b1 = ld8(&sb[((size_t)(br16 + 1) * 128 + k32) * 512 + lanelin]);
    acc[0][0] = mfma16(a0, b0, acc[0][0]);
    acc[0][1] = mfma16(a0, b1, acc[0][1]);
    acc[1][0] = mfma16(a1, b0, acc[1][0]);
    acc[1][1] = mfma16(a1, b1, acc[1][1]);
  }
  float* ep = e_part + ((size_t)(ks * B_ + b)) * C_ * C_;
#pragma unroll
  for (int i = 0; i < 2; ++i)
#pragma unroll
    for (int j = 0; j < 2; ++j)
#pragma unroll
      for (int r = 0; r < 4; ++r) {
        int cl = cw * 32 + i * 16 + quad * 4 + r;
        int dl = dw * 32 + j * 16 + la;
        float v = acc[i][j][r] * SCALE_CAM;
        ep[(size_t)(c0 + cl) * C_ + d0 + dl] = v;
        tr[dl * 65 + cl] = v;
      }
  if (ci != di) {  // mirror tile (block-uniform branch)
    __syncthreads();
#pragma unroll
    for (int u = t; u < 4096; u += 256) {
      int dl = u >> 6, cl = u & 63;
      ep[(size_t)(d0 + dl) * C_ + c0 + cl] = tr[dl * 65 + cl];
    }
  }
}

// ---------------------------------------------------------------------------
// K_cam_softmax: min-trick softmax over 4 parts -> attn_pk PK(512,512).
// ---------------------------------------------------------------------------
__global__ __launch_bounds__(64) void k_cam_softmax(const float* __restrict__ e_part,
                                                    unsigned short* __restrict__ attn_pk) {
  const int c = blockIdx.x, b = blockIdx.y, lane = threadIdx.x;
  size_t roff = ((size_t)b * C_ + c) * C_;
  float vals[8];
#pragma unroll
  for (int r = 0; r < 8; ++r) {
    int d = lane + r * 64;
    float s = 0.f;
#pragma unroll
    for (int p = 0; p < 4; ++p) s += e_part[(size_t)(p * B_) * C_ * C_ + roff + d];
    vals[r] = s;
  }
  float mn = vals[0];
#pragma unroll
  for (int r = 1; r < 8; ++r) mn = fminf(mn, vals[r]);
#pragma unroll
  for (int m = 32; m >= 1; m >>= 1) mn = fminf(mn, __shfl_xor(mn, m));
  float sum = 0.f;
#pragma unroll
  for (int r = 0; r < 8; ++r) { vals[r] = __expf(mn - vals[r]); sum += vals[r]; }
#pragma unroll
  for (int m = 32; m >= 1; m >>= 1) sum += __shfl_xor(sum, m);
  float sc = (1.0f / (float)C_) / sum;
  unsigned short* ab = attn_pk + (size_t)b * C_ * C_;
#pragma unroll
  for (int r = 0; r < 8; ++r) {
    int d = lane + r * 64;
    size_t go = ((size_t)(c >> 4) * 16 + (d >> 5)) * 512 + (c & 15) * 32 + (d & 31);
    ab[go] = f2bf(vals[r] * sc);
  }
}

// ---------------------------------------------------------------------------
// K_cam_out v21 (verified): 256c x 128n tile -> saT/attn panels read 2x.
// 512 thr = 8 waves = cw(4x64c) x nw(2x64n); acc[4][4].
// ---------------------------------------------------------------------------
__global__ __launch_bounds__(512) void k_cam_out(
    const unsigned short* __restrict__ attn_pk, const unsigned short* __restrict__ saT_pk,
    const unsigned short* __restrict__ sa_pk, const float* __restrict__ gamma_cam,
    float* __restrict__ out) {
  const int b = blockIdx.z, c0 = blockIdx.y * 256, n0 = blockIdx.x * 128;
  const int t = threadIdx.x, wave = t >> 6, lane = t & 63;
  const int la = lane & 15, quad = lane >> 4;
  const int cw = wave & 3, nw = wave >> 2;  // 4 c-subtiles(64) x 2 n-subtiles(64)
  const int lanelin = la * 32 + quad * 8;
  const unsigned short* ab = attn_pk + (size_t)b * C_ * C_;
  const unsigned short* sTb = saT_pk + (size_t)b * N_ * C_;
  const unsigned short* sb = sa_pk + (size_t)b * C_ * N_;

  v4f acc[4][4];
#pragma unroll
  for (int i = 0; i < 4; ++i)
#pragma unroll
    for (int j = 0; j < 4; ++j) acc[i][j] = (v4f){0.f, 0.f, 0.f, 0.f};

  const int ar16 = (c0 + cw * 64) >> 4;
  const int br16 = (n0 + nw * 64) >> 4;
#pragma unroll 2
  for (int s = 0; s < 16; ++s) {
    v8s bfr[4], afr[4];
#pragma unroll
    for (int j = 0; j < 4; ++j)
      bfr[j] = ld8(&sTb[((size_t)(br16 + j) * 16 + s) * 512 + lanelin]);
#pragma unroll
    for (int i = 0; i < 4; ++i)
      afr[i] = ld8(&ab[((size_t)(ar16 + i) * 16 + s) * 512 + lanelin]);
#pragma unroll
    for (int i = 0; i < 4; ++i)
#pragma unroll
      for (int j = 0; j < 4; ++j)
        acc[i][j] = mfma16(afr[i], bfr[j], acc[i][j]);
  }
  const float gc = gamma_cam[0];
#pragma unroll
  for (int ci = 0; ci < 4; ++ci)
#pragma unroll
    for (int nj = 0; nj < 4; ++nj)
#pragma unroll
      for (int r = 0; r < 4; ++r) {
        int c = c0 + cw * 64 + ci * 16 + quad * 4 + r;
        int n = n0 + nw * 64 + nj * 16 + la;
        size_t pko = ((size_t)(c >> 4) * 128 + (n >> 5)) * 512 + (c & 15) * 32 + (n & 31);
        out[((size_t)b * C_ + c) * N_ + n] = fmaf(gc, acc[ci][nj][r], bf2f(sb[pko]));
      }
}

// ---------------------------------------------------------------------------
extern "C" void kernel_launch(void* const* d_in, const int* in_sizes, int n_in,
                              void* d_out, int out_size, void* d_ws, size_t ws_size,
                              hipStream_t stream) {
  const float* x  = (const float*)d_in[0];
  const float* wq = (const float*)d_in[1];
  const float* bq = (const float*)d_in[2];
  const float* wk = (const float*)d_in[3];
  const float* bk = (const float*)d_in[4];
  const float* wv = (const float*)d_in[5];
  const float* bv = (const float*)d_in[6];
  const float* gp = (const float*)d_in[7];
  const float* gc = (const float*)d_in[8];
  float* out = (float*)d_out;

  char* ws = (char*)d_ws;
  // Region map (max used = 84.9 MB):
  //  A 0        : x_pk (16.78M)   -> later at_pk (2.1M)
  //  B 16.78M   : w_pk (1.05M)
  //  C 17.83M   : q_pk (8.39M)    (live through k_pam)
  //  D 26.21M   : k_pk (8.39M)    (live through k_pam)
  //  E 34.60M   : v_pk (16.78M)   -> later ep (16.78M)
  //  F 51.38M   : sa_pk (16.78M)
  //  G 68.16M   : saT_pk (16.78M)
  unsigned short* x_pk   = (unsigned short*)(ws);
  unsigned short* w_pk   = (unsigned short*)(ws + 16777216);
  unsigned short* q_pk   = (unsigned short*)(ws + 17825792);
  unsigned short* k_pk   = (unsigned short*)(ws + 26214400);
  unsigned short* v_pk   = (unsigned short*)(ws + 34603008);
  unsigned short* sa_pk  = (unsigned short*)(ws + 51380224);
  unsigned short* saT_pk = (unsigned short*)(ws + 68157440);
  float*          ep     = (float*)(ws + 34603008);            // reuse E
  unsigned short* at_pk  = (unsigned short*)(ws);              // reuse A

  k_prep<<<2304, 256, 0, stream>>>(x, wq, wk, wv, x_pk, w_pk);
  k_qkv<<<dim3(16, 4, B_), 512, 0, stream>>>(w_pk, x_pk, bq, bk, bv, q_pk, k_pk, v_pk);
  k_pam<<<256, 1024, 0, stream>>>(q_pk, k_pk, v_pk, x, gp, sa_pk, saT_pk);
  k_cam_e<<<dim3(36, 4, B_), 256, 0, stream>>>(sa_pk, ep);
  k_cam_softmax<<<dim3(C_, B_), 64, 0, stream>>>(ep, at_pk);
  k_cam_out<<<dim3(32, 2, B_), 512, 0, stream>>>(at_pk, saT_pk, sa_pk, gc, out);
}